// Round 1
// baseline (913.879 us; speedup 1.0000x reference)
//
#include <hip/hip_runtime.h>
#include <hip/hip_bf16.h>

// ---------- constants ----------
#define D_MODEL   1024
#define D_STATE   16
#define D_CONV    4
#define HEADDIM   64
#define NHEADS    32
#define D_INNER   2048
#define CONV_DIM  2080           // D_INNER + 2*D_STATE
#define D_IN_PROJ 4160           // 2*D_INNER + 2*D_STATE + NHEADS
#define NPAD      4224           // D_IN_PROJ padded to x128
#define BATCH     4
#define SEQLEN    2048
#define MROWS     (BATCH*SEQLEN) // 8192

// ---------- helpers ----------
__device__ __forceinline__ unsigned short f2b(float f) {
    union { float f; unsigned int u; } v; v.f = f;
    unsigned int r = (v.u + 0x7FFFu + ((v.u >> 16) & 1u)) >> 16;
    return (unsigned short)r;
}
__device__ __forceinline__ float b2f(unsigned short h) {
    union { unsigned int u; float f; } v; v.u = ((unsigned int)h) << 16;
    return v.f;
}

typedef __attribute__((ext_vector_type(8))) short bf16x8;
typedef __attribute__((ext_vector_type(4))) float f32x4;

__device__ __forceinline__ void async_copy16(const unsigned short* g, unsigned short* l) {
    __builtin_amdgcn_global_load_lds(
        (const __attribute__((address_space(1))) void*)g,
        (__attribute__((address_space(3))) void*)l, 16, 0, 0);
}

// ---------- 1. cast fp32 -> bf16 ----------
__global__ void cast_f32_bf16(const float* __restrict__ in, unsigned short* __restrict__ out, int n) {
    int i = (blockIdx.x * blockDim.x + threadIdx.x) * 4;
    if (i >= n) return;
    float4 v = *(const float4*)&in[i];
    ushort4 o;
    o.x = f2b(v.x); o.y = f2b(v.y); o.z = f2b(v.z); o.w = f2b(v.w);
    *(ushort4*)&out[i] = o;
}

// ---------- 2. transpose + cast: W[K][N] fp32 -> WT[Np][K] bf16 (zero pad rows N..Np) ----------
__global__ void transpose_cast(const float* __restrict__ W, unsigned short* __restrict__ WT,
                               int K, int N) {
    __shared__ float tile[64][65];
    int n0 = blockIdx.x * 64, k0 = blockIdx.y * 64;
    int tx = threadIdx.x & 63, ty = threadIdx.x >> 6; // wave id 0..3
    #pragma unroll
    for (int i = 0; i < 16; i++) {
        int r = ty * 16 + i;             // k-offset in tile
        int n = n0 + tx;
        float v = (n < N) ? W[(size_t)(k0 + r) * N + n] : 0.f;
        tile[r][tx] = v;
    }
    __syncthreads();
    #pragma unroll
    for (int i = 0; i < 16; i++) {
        int r = ty * 16 + i;             // n-offset in tile
        WT[(size_t)(n0 + r) * K + k0 + tx] = f2b(tile[tx][r]);
    }
}

// ---------- 3. bf16 MFMA GEMM: C[M][N] = A[M][K] * B^T  (B stored [N][K]) ----------
// EPI 0: store bf16 to Cb (ldc = N).  EPI 1: out[m*1024+n] = xres[...] + acc*ls[n] (fp32)
template <int EPI>
__global__ __launch_bounds__(256)
void gemm_bf16(const unsigned short* __restrict__ A, const unsigned short* __restrict__ B,
               int K, int N, unsigned short* __restrict__ Cb,
               float* __restrict__ Cf, const float* __restrict__ xres,
               const float* __restrict__ ls) {
    __shared__ unsigned short lds_a[128 * 32];
    __shared__ unsigned short lds_b[128 * 32];
    const int tid  = threadIdx.x;
    const int wave = tid >> 6;
    const int lane = tid & 63;
    const int bm = blockIdx.y, bn = blockIdx.x;
    const int wm = wave >> 1, wn = wave & 1;

    f32x4 acc[4][4];
    #pragma unroll
    for (int i = 0; i < 4; i++)
        #pragma unroll
        for (int j = 0; j < 4; j++) acc[i][j] = (f32x4){0.f, 0.f, 0.f, 0.f};

    const int r0   = tid >> 2;          // 0..63
    const int cseg = (tid & 3) * 8;
    const unsigned short* gA = A + (size_t)(bm * 128 + r0) * K + cseg;
    const unsigned short* gB = B + (size_t)(bn * 128 + r0) * K + cseg;

    for (int k0 = 0; k0 < K; k0 += 32) {
        async_copy16(gA + k0,                 &lds_a[wave * 512]);
        async_copy16(gA + k0 + (size_t)64*K,  &lds_a[2048 + wave * 512]);
        async_copy16(gB + k0,                 &lds_b[wave * 512]);
        async_copy16(gB + k0 + (size_t)64*K,  &lds_b[2048 + wave * 512]);
        __syncthreads();

        bf16x8 af[4], bfr[4];
        const int lm = lane & 15, lq = (lane >> 4) * 8;
        #pragma unroll
        for (int i = 0; i < 4; i++)
            af[i] = *(const bf16x8*)&lds_a[(wm * 64 + i * 16 + lm) * 32 + lq];
        #pragma unroll
        for (int j = 0; j < 4; j++)
            bfr[j] = *(const bf16x8*)&lds_b[(wn * 64 + j * 16 + lm) * 32 + lq];
        #pragma unroll
        for (int i = 0; i < 4; i++)
            #pragma unroll
            for (int j = 0; j < 4; j++)
                acc[i][j] = __builtin_amdgcn_mfma_f32_16x16x32_bf16(af[i], bfr[j], acc[i][j], 0, 0, 0);
        __syncthreads();
    }

    const int row0 = bm * 128 + wm * 64;
    const int col0 = bn * 128 + wn * 64;
    const int lm = lane & 15, lq = (lane >> 4) * 4;
    #pragma unroll
    for (int i = 0; i < 4; i++) {
        #pragma unroll
        for (int j = 0; j < 4; j++) {
            #pragma unroll
            for (int r = 0; r < 4; r++) {
                int gr = row0 + i * 16 + lq + r;
                int gc = col0 + j * 16 + lm;
                float v = acc[i][j][r];
                if (EPI == 0) {
                    Cb[(size_t)gr * N + gc] = f2b(v);
                } else {
                    size_t idx = (size_t)gr * 1024 + gc;
                    Cf[idx] = xres[idx] + v * ls[gc];
                }
            }
        }
    }
}

// ---------- 4. conv + silu + dt/dA ----------
__global__ __launch_bounds__(256)
void conv_dt_kernel(const unsigned short* __restrict__ zx,
                    const float* __restrict__ conv_w, const float* __restrict__ conv_b,
                    const float* __restrict__ dt_bias, const float* __restrict__ A_log,
                    unsigned short* __restrict__ xbc_out,
                    float* __restrict__ dt_out, float* __restrict__ dA_out) {
    int bl = blockIdx.x;                // 0..8191
    int b = bl >> 11, l = bl & 2047;
    for (int c = threadIdx.x; c < CONV_DIM; c += 256) {
        float acc = conv_b[c];
        #pragma unroll
        for (int k = 0; k < 4; k++) {
            int t = l - 3 + k;
            if (t >= 0) {
                float xv = b2f(zx[(size_t)(b * SEQLEN + t) * NPAD + D_INNER + c]);
                acc += xv * conv_w[c * 4 + k];
            }
        }
        float s = acc / (1.f + __expf(-acc));
        xbc_out[(size_t)bl * CONV_DIM + c] = f2b(s);
    }
    if (threadIdx.x < NHEADS) {
        int h = threadIdx.x;
        float raw = b2f(zx[(size_t)bl * NPAD + D_INNER + CONV_DIM + h]) + dt_bias[h];
        float dtv = (raw > 20.f) ? raw : log1pf(__expf(raw));
        float Ah = -__expf(A_log[h]);
        dt_out[(size_t)bl * NHEADS + h] = dtv;
        dA_out[(size_t)bl * NHEADS + h] = __expf(dtv * Ah);
    }
}

// ---------- 5. selective scan: 1 block per (b,head), thread owns h[p][n] ----------
__global__ __launch_bounds__(1024)
void scan_kernel(const unsigned short* __restrict__ xbc,
                 const float* __restrict__ dt, const float* __restrict__ dA,
                 const float* __restrict__ Dp, unsigned short* __restrict__ y) {
    const int b = blockIdx.x >> 5, h = blockIdx.x & 31;
    const int tid = threadIdx.x;
    const int p = tid >> 4, n = tid & 15;
    __shared__ unsigned short s_xs[64][64];
    __shared__ unsigned short s_bc[64][32];
    __shared__ float s_dt[64], s_da[64];
    float hst = 0.f;
    const float Dh = Dp[h];

    for (int c0 = 0; c0 < SEQLEN; c0 += 64) {
        {   // xs chunk: 64 rows x 64 cols, ushort4 per thread
            int r = tid >> 4, cc = (tid & 15) * 4;
            const unsigned short* src =
                &xbc[(size_t)(b * SEQLEN + c0 + r) * CONV_DIM + h * 64 + cc];
            *(ushort4*)&s_xs[r][cc] = *(const ushort4*)src;
        }
        {   // B (16) + C (16) per row
            int r = tid >> 5, cc = tid & 31;
            if (tid < 2048)
                s_bc[r][cc] = xbc[(size_t)(b * SEQLEN + c0 + r) * CONV_DIM + D_INNER + cc];
        }
        if (tid < 64)       s_dt[tid]      = dt[(size_t)(b * SEQLEN + c0 + tid) * NHEADS + h];
        else if (tid < 128) s_da[tid - 64] = dA[(size_t)(b * SEQLEN + c0 + tid - 64) * NHEADS + h];
        __syncthreads();

        for (int i = 0; i < 64; i++) {
            float xs = b2f(s_xs[i][p]);
            float Bn = b2f(s_bc[i][n]);
            float Cn = b2f(s_bc[i][16 + n]);
            hst = hst * s_da[i] + (s_dt[i] * xs) * Bn;
            float part = hst * Cn;
            part += __shfl_xor(part, 1, 16);
            part += __shfl_xor(part, 2, 16);
            part += __shfl_xor(part, 4, 16);
            part += __shfl_xor(part, 8, 16);
            if (n == 0)
                y[(size_t)(b * SEQLEN + c0 + i) * D_INNER + h * 64 + p] = f2b(part + Dh * xs);
        }
        __syncthreads();
    }
}

// ---------- 6. gated RMSNorm (in-place ok): yn = (y*silu(z)) * rsqrt(mean+eps) * w ----------
__global__ __launch_bounds__(256)
void norm_kernel(const unsigned short* __restrict__ y, const unsigned short* __restrict__ zx,
                 const float* __restrict__ norm_w, unsigned short* __restrict__ yn) {
    int row = blockIdx.x;
    int tid = threadIdx.x;
    int base = tid * 8;
    const unsigned short* yr = &y[(size_t)row * D_INNER];
    const unsigned short* zr = &zx[(size_t)row * NPAD];
    ushort4 ya = *(const ushort4*)&yr[base];
    ushort4 yb = *(const ushort4*)&yr[base + 4];
    ushort4 za = *(const ushort4*)&zr[base];
    ushort4 zb = *(const ushort4*)&zr[base + 4];
    float yv[8] = { b2f(ya.x), b2f(ya.y), b2f(ya.z), b2f(ya.w),
                    b2f(yb.x), b2f(yb.y), b2f(yb.z), b2f(yb.w) };
    float zv[8] = { b2f(za.x), b2f(za.y), b2f(za.z), b2f(za.w),
                    b2f(zb.x), b2f(zb.y), b2f(zb.z), b2f(zb.w) };
    float v[8]; float ss = 0.f;
    #pragma unroll
    for (int k = 0; k < 8; k++) {
        float z = zv[k];
        float s = z / (1.f + __expf(-z));
        v[k] = yv[k] * s;
        ss += v[k] * v[k];
    }
    #pragma unroll
    for (int o = 32; o > 0; o >>= 1) ss += __shfl_xor(ss, o, 64);
    __shared__ float sred[4];
    if ((tid & 63) == 0) sred[tid >> 6] = ss;
    __syncthreads();
    float total = sred[0] + sred[1] + sred[2] + sred[3];
    float scale = rsqrtf(total * (1.f / D_INNER) + 1e-5f);
    ushort4 oa, ob;
    oa.x = f2b(v[0] * scale * norm_w[base + 0]);
    oa.y = f2b(v[1] * scale * norm_w[base + 1]);
    oa.z = f2b(v[2] * scale * norm_w[base + 2]);
    oa.w = f2b(v[3] * scale * norm_w[base + 3]);
    ob.x = f2b(v[4] * scale * norm_w[base + 4]);
    ob.y = f2b(v[5] * scale * norm_w[base + 5]);
    ob.z = f2b(v[6] * scale * norm_w[base + 6]);
    ob.w = f2b(v[7] * scale * norm_w[base + 7]);
    unsigned short* out = &yn[(size_t)row * D_INNER];
    *(ushort4*)&out[base] = oa;
    *(ushort4*)&out[base + 4] = ob;
}

// ---------- launcher ----------
extern "C" void kernel_launch(void* const* d_in, const int* in_sizes, int n_in,
                              void* d_out, int out_size, void* d_ws, size_t ws_size,
                              hipStream_t stream) {
    const float* x        = (const float*)d_in[0];
    const float* W_in     = (const float*)d_in[1];
    const float* conv_w   = (const float*)d_in[2];
    const float* conv_b   = (const float*)d_in[3];
    const float* dt_bias  = (const float*)d_in[4];
    const float* A_log    = (const float*)d_in[5];
    const float* D_param  = (const float*)d_in[6];
    const float* norm_w   = (const float*)d_in[7];
    const float* W_out    = (const float*)d_in[8];
    const float* ls       = (const float*)d_in[9];
    float* out = (float*)d_out;

    char* ws = (char*)d_ws;
    size_t off = 0;
    unsigned short* x_bf  = (unsigned short*)(ws + off); off += (size_t)MROWS * D_MODEL * 2;   // 16.8 MB
    unsigned short* winT  = (unsigned short*)(ws + off); off += (size_t)NPAD * D_MODEL * 2;    // 8.7 MB
    unsigned short* woutT = (unsigned short*)(ws + off); off += (size_t)D_MODEL * D_INNER * 2; // 4.2 MB
    unsigned short* zx    = (unsigned short*)(ws + off); off += (size_t)MROWS * NPAD * 2;      // 69.2 MB
    unsigned short* xbc   = (unsigned short*)(ws + off); off += (size_t)MROWS * CONV_DIM * 2;  // 34.1 MB
    float*          dtb   = (float*)(ws + off);          off += (size_t)MROWS * NHEADS * 4;    // 1 MB
    float*          dab   = (float*)(ws + off);          off += (size_t)MROWS * NHEADS * 4;    // 1 MB
    unsigned short* yb    = (unsigned short*)(ws + off); off += (size_t)MROWS * D_INNER * 2;   // 33.6 MB

    // 1. x -> bf16
    cast_f32_bf16<<<(MROWS * D_MODEL) / 1024, 256, 0, stream>>>(x, x_bf, MROWS * D_MODEL);
    // 2. W_in^T (pad 4160->4224 with zeros), W_out^T
    transpose_cast<<<dim3(NPAD / 64, D_MODEL / 64), 256, 0, stream>>>(W_in, winT, D_MODEL, D_IN_PROJ);
    transpose_cast<<<dim3(D_MODEL / 64, D_INNER / 64), 256, 0, stream>>>(W_out, woutT, D_INNER, D_MODEL);
    // 3. GEMM1: zx[8192][4224] = x_bf @ winT^T
    gemm_bf16<0><<<dim3(NPAD / 128, MROWS / 128), 256, 0, stream>>>(
        x_bf, winT, D_MODEL, NPAD, zx, nullptr, nullptr, nullptr);
    // 4. conv + dt
    conv_dt_kernel<<<MROWS, 256, 0, stream>>>(zx, conv_w, conv_b, dt_bias, A_log, xbc, dtb, dab);
    // 5. scan
    scan_kernel<<<BATCH * NHEADS, 1024, 0, stream>>>(xbc, dtb, dab, D_param, yb);
    // 6. gated RMSNorm (in-place on yb)
    norm_kernel<<<MROWS, 256, 0, stream>>>(yb, zx, norm_w, yb);
    // 7. GEMM2 + residual epilogue -> d_out
    gemm_bf16<1><<<dim3(D_MODEL / 128, MROWS / 128), 256, 0, stream>>>(
        yb, woutT, D_INNER, D_MODEL, nullptr, out, x, ls);
}

// Round 2
// 434.001 us; speedup vs baseline: 2.1057x; 2.1057x over previous
//
#include <hip/hip_runtime.h>
#include <hip/hip_bf16.h>

// ---------- constants ----------
#define D_MODEL   1024
#define D_STATE   16
#define D_CONV    4
#define HEADDIM   64
#define NHEADS    32
#define D_INNER   2048
#define CONV_DIM  2080           // D_INNER + 2*D_STATE
#define D_IN_PROJ 4160           // 2*D_INNER + 2*D_STATE + NHEADS
#define NPAD      4224           // D_IN_PROJ padded to x128
#define BATCH     4
#define SEQLEN    2048
#define MROWS     (BATCH*SEQLEN) // 8192
#define QCHUNK    64
#define NCHUNK    (SEQLEN/QCHUNK) // 32

// ---------- helpers ----------
__device__ __forceinline__ unsigned short f2b(float f) {
    union { float f; unsigned int u; } v; v.f = f;
    unsigned int r = (v.u + 0x7FFFu + ((v.u >> 16) & 1u)) >> 16;
    return (unsigned short)r;
}
__device__ __forceinline__ float b2f(unsigned short h) {
    union { unsigned int u; float f; } v; v.u = ((unsigned int)h) << 16;
    return v.f;
}

typedef __attribute__((ext_vector_type(8))) short bf16x8;
typedef __attribute__((ext_vector_type(4))) float f32x4;

__device__ __forceinline__ void async_copy16(const unsigned short* g, unsigned short* l) {
    __builtin_amdgcn_global_load_lds(
        (const __attribute__((address_space(1))) void*)g,
        (__attribute__((address_space(3))) void*)l, 16, 0, 0);
}

// ---------- 1. cast fp32 -> bf16 ----------
__global__ void cast_f32_bf16(const float* __restrict__ in, unsigned short* __restrict__ out, int n) {
    int i = (blockIdx.x * blockDim.x + threadIdx.x) * 4;
    if (i >= n) return;
    float4 v = *(const float4*)&in[i];
    ushort4 o;
    o.x = f2b(v.x); o.y = f2b(v.y); o.z = f2b(v.z); o.w = f2b(v.w);
    *(ushort4*)&out[i] = o;
}

// ---------- 2. transpose + cast: W[K][N] fp32 -> WT[Np][K] bf16 ----------
__global__ void transpose_cast(const float* __restrict__ W, unsigned short* __restrict__ WT,
                               int K, int N) {
    __shared__ float tile[64][65];
    int n0 = blockIdx.x * 64, k0 = blockIdx.y * 64;
    int tx = threadIdx.x & 63, ty = threadIdx.x >> 6;
    #pragma unroll
    for (int i = 0; i < 16; i++) {
        int r = ty * 16 + i;
        int n = n0 + tx;
        float v = (n < N) ? W[(size_t)(k0 + r) * N + n] : 0.f;
        tile[r][tx] = v;
    }
    __syncthreads();
    #pragma unroll
    for (int i = 0; i < 16; i++) {
        int r = ty * 16 + i;
        WT[(size_t)(n0 + r) * K + k0 + tx] = f2b(tile[tx][r]);
    }
}

// ---------- 3. bf16 MFMA GEMM: C[M][N] = A[M][K] * B^T ----------
template <int EPI>
__global__ __launch_bounds__(256)
void gemm_bf16(const unsigned short* __restrict__ A, const unsigned short* __restrict__ B,
               int K, int N, unsigned short* __restrict__ Cb,
               float* __restrict__ Cf, const float* __restrict__ xres,
               const float* __restrict__ ls) {
    __shared__ unsigned short lds_a[128 * 32];
    __shared__ unsigned short lds_b[128 * 32];
    const int tid  = threadIdx.x;
    const int wave = tid >> 6;
    const int lane = tid & 63;
    const int bm = blockIdx.y, bn = blockIdx.x;
    const int wm = wave >> 1, wn = wave & 1;

    f32x4 acc[4][4];
    #pragma unroll
    for (int i = 0; i < 4; i++)
        #pragma unroll
        for (int j = 0; j < 4; j++) acc[i][j] = (f32x4){0.f, 0.f, 0.f, 0.f};

    const int r0   = tid >> 2;
    const int cseg = (tid & 3) * 8;
    const unsigned short* gA = A + (size_t)(bm * 128 + r0) * K + cseg;
    const unsigned short* gB = B + (size_t)(bn * 128 + r0) * K + cseg;

    for (int k0 = 0; k0 < K; k0 += 32) {
        async_copy16(gA + k0,                 &lds_a[wave * 512]);
        async_copy16(gA + k0 + (size_t)64*K,  &lds_a[2048 + wave * 512]);
        async_copy16(gB + k0,                 &lds_b[wave * 512]);
        async_copy16(gB + k0 + (size_t)64*K,  &lds_b[2048 + wave * 512]);
        __syncthreads();

        bf16x8 af[4], bfr[4];
        const int lm = lane & 15, lq = (lane >> 4) * 8;
        #pragma unroll
        for (int i = 0; i < 4; i++)
            af[i] = *(const bf16x8*)&lds_a[(wm * 64 + i * 16 + lm) * 32 + lq];
        #pragma unroll
        for (int j = 0; j < 4; j++)
            bfr[j] = *(const bf16x8*)&lds_b[(wn * 64 + j * 16 + lm) * 32 + lq];
        #pragma unroll
        for (int i = 0; i < 4; i++)
            #pragma unroll
            for (int j = 0; j < 4; j++)
                acc[i][j] = __builtin_amdgcn_mfma_f32_16x16x32_bf16(af[i], bfr[j], acc[i][j], 0, 0, 0);
        __syncthreads();
    }

    const int row0 = bm * 128 + wm * 64;
    const int col0 = bn * 128 + wn * 64;
    const int lm = lane & 15, lq = (lane >> 4) * 4;
    #pragma unroll
    for (int i = 0; i < 4; i++) {
        #pragma unroll
        for (int j = 0; j < 4; j++) {
            #pragma unroll
            for (int r = 0; r < 4; r++) {
                int gr = row0 + i * 16 + lq + r;
                int gc = col0 + j * 16 + lm;
                float v = acc[i][j][r];
                if (EPI == 0) {
                    Cb[(size_t)gr * N + gc] = f2b(v);
                } else {
                    size_t idx = (size_t)gr * 1024 + gc;
                    Cf[idx] = xres[idx] + v * ls[gc];
                }
            }
        }
    }
}

// ---------- 4. conv + silu + dt ----------
__global__ __launch_bounds__(256)
void conv_dt_kernel(const unsigned short* __restrict__ zx,
                    const float* __restrict__ conv_w, const float* __restrict__ conv_b,
                    const float* __restrict__ dt_bias,
                    unsigned short* __restrict__ xbc_out,
                    float* __restrict__ dt_out) {
    int bl = blockIdx.x;
    int b = bl >> 11, l = bl & 2047;
    for (int c = threadIdx.x; c < CONV_DIM; c += 256) {
        float acc = conv_b[c];
        #pragma unroll
        for (int k = 0; k < 4; k++) {
            int t = l - 3 + k;
            if (t >= 0) {
                float xv = b2f(zx[(size_t)(b * SEQLEN + t) * NPAD + D_INNER + c]);
                acc += xv * conv_w[c * 4 + k];
            }
        }
        float s = acc / (1.f + __expf(-acc));
        xbc_out[(size_t)bl * CONV_DIM + c] = f2b(s);
    }
    if (threadIdx.x < NHEADS) {
        int h = threadIdx.x;
        float raw = b2f(zx[(size_t)bl * NPAD + D_INNER + CONV_DIM + h]) + dt_bias[h];
        float dtv = (raw > 20.f) ? raw : log1pf(__expf(raw));
        dt_out[(size_t)bl * NHEADS + h] = dtv;
    }
}

// ---------- 5a. SSD intra-chunk kernel ----------
// grid: b*h*chunk = 4096 blocks, 256 threads.
// Outputs: y_intra(+D*x) bf16, h_out_local fp32 [bh][c][n][p], P_c, scale[t].
__global__ __launch_bounds__(256)
void ssd_intra(const unsigned short* __restrict__ xbc, const float* __restrict__ dtb,
               const float* __restrict__ A_log, const float* __restrict__ D_param,
               unsigned short* __restrict__ y, float* __restrict__ hbuf,
               float* __restrict__ pbuf, float* __restrict__ sbuf) {
    __shared__ unsigned short sB[64 * 32];    // B, [s][n] pad n to 32 (zeros)
    __shared__ unsigned short sC[64 * 32];    // C, same
    __shared__ unsigned short sXT[64 * 72];   // X^T [p][s], stride 72 (144B, 16B-aligned rows)
    __shared__ unsigned short sM[64 * 72];    // M  [t][s], stride 72
    __shared__ unsigned short sBwT[16 * 72];  // (w.B)^T [n][s]
    __shared__ float sdt[64], scd[64];

    const int blk = blockIdx.x;
    const int c  = blk & 31;
    const int h  = (blk >> 5) & 31;
    const int b  = blk >> 10;
    const int bh = blk >> 5;
    const int row0 = b * SEQLEN + c * QCHUNK;

    const int t    = threadIdx.x;
    const int w    = t >> 6;
    const int lane = t & 63;
    const int lm   = lane & 15;
    const int lq8  = (lane >> 4) * 8;
    const int lq4  = (lane >> 4) * 4;
    const float Ah = -__expf(A_log[h]);

    // ---- load phase ----
    {
        int s = t >> 2, q = t & 3;
        const size_t grow = (size_t)(row0 + s) * CONV_DIM;
        // B / C (8 bf16 each), zero-pad cols 16..31
        {
            union { int4 v; unsigned short u[8]; } bc;
            bc.v = *(const int4*)&xbc[grow + D_INNER + (q >> 1) * 16 + (q & 1) * 8];
            unsigned short* dst = (q < 2 ? sB : sC) + s * 32 + (q & 1) * 8;
            *(int4*)dst = bc.v;
            *(int4*)(dst + 16) = (int4){0, 0, 0, 0};
        }
        // X: 16 cols per thread, transposed into sXT
        {
            int p0 = q * 16;
            union { int4 v; unsigned short u[8]; } xa, xb;
            xa.v = *(const int4*)&xbc[grow + h * 64 + p0];
            xb.v = *(const int4*)&xbc[grow + h * 64 + p0 + 8];
            #pragma unroll
            for (int i = 0; i < 8; i++) sXT[(p0 + i) * 72 + s]     = xa.u[i];
            #pragma unroll
            for (int i = 0; i < 8; i++) sXT[(p0 + 8 + i) * 72 + s] = xb.u[i];
        }
    }
    // dt + inclusive prefix (wave 0 only)
    if (t < 64) {
        float dtv = dtb[(size_t)(row0 + t) * NHEADS + h];
        float v = dtv;
        #pragma unroll
        for (int o = 1; o < 64; o <<= 1) {
            float u = __shfl_up(v, o, 64);
            if (t >= o) v += u;
        }
        sdt[t] = dtv;
        scd[t] = v;
        float sc = __expf(Ah * v);
        sbuf[(size_t)bh * SEQLEN + c * QCHUNK + t] = sc;
        if (t == 63) pbuf[bh * NCHUNK + c] = sc;
    }
    __syncthreads();

    // ---- S = C * B^T (tiles: wave w owns t-rows w*16..w*16+15; sb <= w) ----
    f32x4 sacc[4];
    {
        bf16x8 cfrag = *(const bf16x8*)&sC[(w * 16 + lm) * 32 + lq8];
        #pragma unroll
        for (int sb = 0; sb < 4; sb++) {
            if (sb <= w) {
                bf16x8 bfrag = *(const bf16x8*)&sB[(sb * 16 + lm) * 32 + lq8];
                sacc[sb] = __builtin_amdgcn_mfma_f32_16x16x32_bf16(
                    cfrag, bfrag, (f32x4){0.f, 0.f, 0.f, 0.f}, 0, 0, 0);
            }
        }
    }
    // ---- M[t][s] = mask * S * dt[s] * exp(A*(cd[t]-cd[s])) -> sM (wave-local rows) ----
    #pragma unroll
    for (int sb = 0; sb < 4; sb++) {
        int sp = sb * 16 + lm;
        if (sb > w) {
            #pragma unroll
            for (int r = 0; r < 4; r++) sM[(w * 16 + lq4 + r) * 72 + sp] = 0;
        } else {
            float dts = sdt[sp], cds = scd[sp];
            #pragma unroll
            for (int r = 0; r < 4; r++) {
                int tp = w * 16 + lq4 + r;
                float m = 0.f;
                if (sb < w || sp <= tp)
                    m = sacc[sb][r] * dts * __expf(Ah * (scd[tp] - cds));
                sM[tp * 72 + sp] = f2b(m);
            }
        }
    }
    // ---- Bw^T [n][s] = B[s][n] * dt[s] * exp(A*(cd[63]-cd[s])) ----
    {
        int n = t & 15, s0 = (t >> 4) * 4;
        float cdl = scd[63];
        #pragma unroll
        for (int i = 0; i < 4; i++) {
            int s_ = s0 + i;
            float wgt = sdt[s_] * __expf(Ah * (cdl - scd[s_]));
            sBwT[n * 72 + s_] = f2b(b2f(sB[s_ * 32 + n]) * wgt);
        }
    }
    __syncthreads();

    // ---- Y_intra = M * X  (wave w: t-rows w*16..; pb 0..3; K=64 in 2 steps) ----
    f32x4 yacc[4];
    #pragma unroll
    for (int pb = 0; pb < 4; pb++) yacc[pb] = (f32x4){0.f, 0.f, 0.f, 0.f};
    #pragma unroll
    for (int ks = 0; ks < 2; ks++) {
        if (ks == 1 && w < 2) continue;  // those s-blocks are all zero
        bf16x8 af = *(const bf16x8*)&sM[(w * 16 + lm) * 72 + ks * 32 + lq8];
        #pragma unroll
        for (int pb = 0; pb < 4; pb++) {
            bf16x8 bf_ = *(const bf16x8*)&sXT[(pb * 16 + lm) * 72 + ks * 32 + lq8];
            yacc[pb] = __builtin_amdgcn_mfma_f32_16x16x32_bf16(af, bf_, yacc[pb], 0, 0, 0);
        }
    }
    // ---- h_out_local = Bw^T * X  (wave w owns p-block w) ----
    f32x4 hacc = (f32x4){0.f, 0.f, 0.f, 0.f};
    #pragma unroll
    for (int ks = 0; ks < 2; ks++) {
        bf16x8 af = *(const bf16x8*)&sBwT[lm * 72 + ks * 32 + lq8];
        bf16x8 bf_ = *(const bf16x8*)&sXT[(w * 16 + lm) * 72 + ks * 32 + lq8];
        hacc = __builtin_amdgcn_mfma_f32_16x16x32_bf16(af, bf_, hacc, 0, 0, 0);
    }

    // ---- epilogue ----
    const float Dh = D_param[h];
    #pragma unroll
    for (int pb = 0; pb < 4; pb++) {
        #pragma unroll
        for (int r = 0; r < 4; r++) {
            int tp = w * 16 + lq4 + r;
            int pp = pb * 16 + lm;
            float xv = b2f(sXT[pp * 72 + tp]);
            y[(size_t)(row0 + tp) * D_INNER + h * 64 + pp] = f2b(yacc[pb][r] + Dh * xv);
        }
    }
    #pragma unroll
    for (int r = 0; r < 4; r++)
        hbuf[(size_t)(bh * NCHUNK + c) * 1024 + (lq4 + r) * 64 + (w * 16 + lm)] = hacc[r];
}

// ---------- 5b. inter-chunk state scan (in-place: h_out_local -> h_in) ----------
__global__ __launch_bounds__(1024)
void ssd_state_scan(float* __restrict__ hbuf, const float* __restrict__ pbuf) {
    int bh = blockIdx.x;
    int t = threadIdx.x;
    __shared__ float sP[NCHUNK];
    if (t < NCHUNK) sP[t] = pbuf[bh * NCHUNK + t];
    __syncthreads();
    float carry = 0.f;
    size_t base = (size_t)bh * NCHUNK * 1024 + t;
    #pragma unroll 4
    for (int c = 0; c < NCHUNK; c++) {
        float v = hbuf[base + (size_t)c * 1024];
        hbuf[base + (size_t)c * 1024] = carry;
        carry = v + sP[c] * carry;
    }
}

// ---------- 5c. apply inter-chunk contribution: y += scale[t] * (C_t . h_in) ----------
__global__ __launch_bounds__(64)
void ssd_apply(const unsigned short* __restrict__ xbc, const float* __restrict__ hbuf,
               const float* __restrict__ sbuf, unsigned short* __restrict__ y) {
    __shared__ unsigned short sC2[64 * 32];   // C [t][n] pad 32
    __shared__ unsigned short sHT[64 * 40];   // h_in^T [p][n] pad 32, stride 40 (80B rows)
    __shared__ float sSc[64];

    const int blk = blockIdx.x;
    const int c  = blk & 31;
    const int h  = (blk >> 5) & 31;
    const int b  = blk >> 10;
    const int bh = blk >> 5;
    const int row0 = b * SEQLEN + c * QCHUNK;

    const int lane = threadIdx.x;
    const int lm = lane & 15, lq8 = (lane >> 4) * 8, lq4 = (lane >> 4) * 4;

    // loads
    {
        int s = lane;
        const size_t grow = (size_t)(row0 + s) * CONV_DIM;
        *(int4*)&sC2[s * 32 + 0] = *(const int4*)&xbc[grow + D_INNER + D_STATE];
        *(int4*)&sC2[s * 32 + 8] = *(const int4*)&xbc[grow + D_INNER + D_STATE + 8];
        *(int4*)&sC2[s * 32 + 16] = (int4){0, 0, 0, 0};
        *(int4*)&sC2[s * 32 + 24] = (int4){0, 0, 0, 0};
        size_t hbase = (size_t)(bh * NCHUNK + c) * 1024 + lane;  // p = lane
        #pragma unroll
        for (int n = 0; n < 16; n++)
            sHT[lane * 40 + n] = f2b(hbuf[hbase + n * 64]);
        *(int4*)&sHT[lane * 40 + 16] = (int4){0, 0, 0, 0};
        *(int4*)&sHT[lane * 40 + 24] = (int4){0, 0, 0, 0};
        sSc[lane] = sbuf[(size_t)bh * SEQLEN + c * QCHUNK + lane];
    }
    __syncthreads();

    f32x4 acc[4][4];
    #pragma unroll
    for (int tw = 0; tw < 4; tw++) {
        bf16x8 af = *(const bf16x8*)&sC2[(tw * 16 + lm) * 32 + lq8];
        #pragma unroll
        for (int pb = 0; pb < 4; pb++) {
            bf16x8 bf_ = *(const bf16x8*)&sHT[(pb * 16 + lm) * 40 + lq8];
            acc[tw][pb] = __builtin_amdgcn_mfma_f32_16x16x32_bf16(
                af, bf_, (f32x4){0.f, 0.f, 0.f, 0.f}, 0, 0, 0);
        }
    }
    #pragma unroll
    for (int tw = 0; tw < 4; tw++) {
        #pragma unroll
        for (int pb = 0; pb < 4; pb++) {
            #pragma unroll
            for (int r = 0; r < 4; r++) {
                int tp = tw * 16 + lq4 + r;
                int pp = pb * 16 + lm;
                size_t idx = (size_t)(row0 + tp) * D_INNER + h * 64 + pp;
                y[idx] = f2b(b2f(y[idx]) + acc[tw][pb][r] * sSc[tp]);
            }
        }
    }
}

// ---------- 6. gated RMSNorm ----------
__global__ __launch_bounds__(256)
void norm_kernel(const unsigned short* __restrict__ y, const unsigned short* __restrict__ zx,
                 const float* __restrict__ norm_w, unsigned short* __restrict__ yn) {
    int row = blockIdx.x;
    int tid = threadIdx.x;
    int base = tid * 8;
    const unsigned short* yr = &y[(size_t)row * D_INNER];
    const unsigned short* zr = &zx[(size_t)row * NPAD];
    ushort4 ya = *(const ushort4*)&yr[base];
    ushort4 yb = *(const ushort4*)&yr[base + 4];
    ushort4 za = *(const ushort4*)&zr[base];
    ushort4 zb = *(const ushort4*)&zr[base + 4];
    float yv[8] = { b2f(ya.x), b2f(ya.y), b2f(ya.z), b2f(ya.w),
                    b2f(yb.x), b2f(yb.y), b2f(yb.z), b2f(yb.w) };
    float zv[8] = { b2f(za.x), b2f(za.y), b2f(za.z), b2f(za.w),
                    b2f(zb.x), b2f(zb.y), b2f(zb.z), b2f(zb.w) };
    float v[8]; float ss = 0.f;
    #pragma unroll
    for (int k = 0; k < 8; k++) {
        float z = zv[k];
        float s = z / (1.f + __expf(-z));
        v[k] = yv[k] * s;
        ss += v[k] * v[k];
    }
    #pragma unroll
    for (int o = 32; o > 0; o >>= 1) ss += __shfl_xor(ss, o, 64);
    __shared__ float sred[4];
    if ((tid & 63) == 0) sred[tid >> 6] = ss;
    __syncthreads();
    float total = sred[0] + sred[1] + sred[2] + sred[3];
    float scale = rsqrtf(total * (1.f / D_INNER) + 1e-5f);
    ushort4 oa, ob;
    oa.x = f2b(v[0] * scale * norm_w[base + 0]);
    oa.y = f2b(v[1] * scale * norm_w[base + 1]);
    oa.z = f2b(v[2] * scale * norm_w[base + 2]);
    oa.w = f2b(v[3] * scale * norm_w[base + 3]);
    ob.x = f2b(v[4] * scale * norm_w[base + 4]);
    ob.y = f2b(v[5] * scale * norm_w[base + 5]);
    ob.z = f2b(v[6] * scale * norm_w[base + 6]);
    ob.w = f2b(v[7] * scale * norm_w[base + 7]);
    unsigned short* out = &yn[(size_t)row * D_INNER];
    *(ushort4*)&out[base] = oa;
    *(ushort4*)&out[base + 4] = ob;
}

// ---------- launcher ----------
extern "C" void kernel_launch(void* const* d_in, const int* in_sizes, int n_in,
                              void* d_out, int out_size, void* d_ws, size_t ws_size,
                              hipStream_t stream) {
    const float* x        = (const float*)d_in[0];
    const float* W_in     = (const float*)d_in[1];
    const float* conv_w   = (const float*)d_in[2];
    const float* conv_b   = (const float*)d_in[3];
    const float* dt_bias  = (const float*)d_in[4];
    const float* A_log    = (const float*)d_in[5];
    const float* D_param  = (const float*)d_in[6];
    const float* norm_w   = (const float*)d_in[7];
    const float* W_out    = (const float*)d_in[8];
    const float* ls       = (const float*)d_in[9];
    float* out = (float*)d_out;

    char* ws = (char*)d_ws;
    size_t off = 0;
    unsigned short* x_bf  = (unsigned short*)(ws + off); off += (size_t)MROWS * D_MODEL * 2;   // 16.8 MB (reused as hbuf)
    unsigned short* winT  = (unsigned short*)(ws + off); off += (size_t)NPAD * D_MODEL * 2;
    unsigned short* woutT = (unsigned short*)(ws + off); off += (size_t)D_MODEL * D_INNER * 2;
    unsigned short* zx    = (unsigned short*)(ws + off); off += (size_t)MROWS * NPAD * 2;
    unsigned short* xbc   = (unsigned short*)(ws + off); off += (size_t)MROWS * CONV_DIM * 2;
    float*          dtb   = (float*)(ws + off);          off += (size_t)MROWS * NHEADS * 4;
    float*          sbuf  = (float*)(ws + off);          off += (size_t)MROWS * NHEADS * 4;    // scale[t] per (b,h,t)... 1 MB
    float*          pbuf  = (float*)(ws + off);          off += (size_t)BATCH * NHEADS * NCHUNK * 4;
    unsigned short* yb    = (unsigned short*)(ws + off); off += (size_t)MROWS * D_INNER * 2;
    // hbuf aliases x_bf: x_bf is dead after GEMM1; sizes match exactly (16,777,216 B).
    float* hbuf = (float*)x_bf;

    // 1. x -> bf16
    cast_f32_bf16<<<(MROWS * D_MODEL) / 1024, 256, 0, stream>>>(x, x_bf, MROWS * D_MODEL);
    // 2. transposes
    transpose_cast<<<dim3(NPAD / 64, D_MODEL / 64), 256, 0, stream>>>(W_in, winT, D_MODEL, D_IN_PROJ);
    transpose_cast<<<dim3(D_MODEL / 64, D_INNER / 64), 256, 0, stream>>>(W_out, woutT, D_INNER, D_MODEL);
    // 3. GEMM1
    gemm_bf16<0><<<dim3(NPAD / 128, MROWS / 128), 256, 0, stream>>>(
        x_bf, winT, D_MODEL, NPAD, zx, nullptr, nullptr, nullptr);
    // 4. conv + dt
    conv_dt_kernel<<<MROWS, 256, 0, stream>>>(zx, conv_w, conv_b, dt_bias, xbc, dtb);
    // 5. SSD chunked scan
    ssd_intra<<<BATCH * NHEADS * NCHUNK, 256, 0, stream>>>(
        xbc, dtb, A_log, D_param, yb, hbuf, pbuf, sbuf);
    ssd_state_scan<<<BATCH * NHEADS, 1024, 0, stream>>>(hbuf, pbuf);
    ssd_apply<<<BATCH * NHEADS * NCHUNK, 64, 0, stream>>>(xbc, hbuf, sbuf, yb);
    // 6. gated RMSNorm
    norm_kernel<<<MROWS, 256, 0, stream>>>(yb, zx, norm_w, yb);
    // 7. GEMM2 + residual
    gemm_bf16<1><<<dim3(D_MODEL / 128, MROWS / 128), 256, 0, stream>>>(
        yb, woutT, D_INNER, D_MODEL, nullptr, out, x, ls);
}

// Round 3
// 406.889 us; speedup vs baseline: 2.2460x; 1.0666x over previous
//
#include <hip/hip_runtime.h>
#include <hip/hip_bf16.h>

// ---------- constants ----------
#define D_MODEL   1024
#define D_STATE   16
#define D_CONV    4
#define HEADDIM   64
#define NHEADS    32
#define D_INNER   2048
#define CONV_DIM  2080           // D_INNER + 2*D_STATE
#define D_IN_PROJ 4160           // 2*D_INNER + 2*D_STATE + NHEADS
#define NPAD      4224           // D_IN_PROJ padded to x128
#define BATCH     4
#define SEQLEN    2048
#define MROWS     (BATCH*SEQLEN) // 8192
#define QCHUNK    64
#define NCHUNK    (SEQLEN/QCHUNK) // 32

// ---------- helpers ----------
__device__ __forceinline__ unsigned short f2b(float f) {
    union { float f; unsigned int u; } v; v.f = f;
    unsigned int r = (v.u + 0x7FFFu + ((v.u >> 16) & 1u)) >> 16;
    return (unsigned short)r;
}
__device__ __forceinline__ float b2f(unsigned short h) {
    union { unsigned int u; float f; } v; v.u = ((unsigned int)h) << 16;
    return v.f;
}

typedef __attribute__((ext_vector_type(8))) short bf16x8;
typedef __attribute__((ext_vector_type(4))) float f32x4;

__device__ __forceinline__ void async_copy16(const unsigned short* g, unsigned short* l) {
    __builtin_amdgcn_global_load_lds(
        (const __attribute__((address_space(1))) void*)g,
        (__attribute__((address_space(3))) void*)l, 16, 0, 0);
}

// ---------- 1. cast fp32 -> bf16 ----------
__global__ void cast_f32_bf16(const float* __restrict__ in, unsigned short* __restrict__ out, int n) {
    int i = (blockIdx.x * blockDim.x + threadIdx.x) * 4;
    if (i >= n) return;
    float4 v = *(const float4*)&in[i];
    ushort4 o;
    o.x = f2b(v.x); o.y = f2b(v.y); o.z = f2b(v.z); o.w = f2b(v.w);
    *(ushort4*)&out[i] = o;
}

// ---------- 2. transpose + cast: W[K][N] fp32 -> WT[Np][K] bf16 ----------
__global__ void transpose_cast(const float* __restrict__ W, unsigned short* __restrict__ WT,
                               int K, int N) {
    __shared__ float tile[64][65];
    int n0 = blockIdx.x * 64, k0 = blockIdx.y * 64;
    int tx = threadIdx.x & 63, ty = threadIdx.x >> 6;
    #pragma unroll
    for (int i = 0; i < 16; i++) {
        int r = ty * 16 + i;
        int n = n0 + tx;
        float v = (n < N) ? W[(size_t)(k0 + r) * N + n] : 0.f;
        tile[r][tx] = v;
    }
    __syncthreads();
    #pragma unroll
    for (int i = 0; i < 16; i++) {
        int r = ty * 16 + i;
        WT[(size_t)(n0 + r) * K + k0 + tx] = f2b(tile[tx][r]);
    }
}

// ---------- 3. bf16 MFMA GEMM, BK=64, XOR-swizzled LDS ----------
// LDS layout: physical 8-short segment p of row r holds logical k-seg (p ^ (r&7)).
// Staged via global_load_lds: lane L writes phys seg L&7 of row base+(L>>3), so the
// global source k-seg is (L&7)^(L>>3).  Reads XOR with (row&7) -> conflict-free-ish.
template <int EPI>
__global__ __launch_bounds__(256)
void gemm_bf16(const unsigned short* __restrict__ A, const unsigned short* __restrict__ B,
               int K, int N, unsigned short* __restrict__ Cb,
               float* __restrict__ Cf, const float* __restrict__ xres,
               const float* __restrict__ ls) {
    __shared__ unsigned short lds_a[128 * 64];
    __shared__ unsigned short lds_b[128 * 64];
    const int tid  = threadIdx.x;
    const int wave = tid >> 6;
    const int lane = tid & 63;
    const int bm = blockIdx.y, bn = blockIdx.x;
    const int wm = wave >> 1, wn = wave & 1;

    f32x4 acc[4][4];
    #pragma unroll
    for (int i = 0; i < 4; i++)
        #pragma unroll
        for (int j = 0; j < 4; j++) acc[i][j] = (f32x4){0.f, 0.f, 0.f, 0.f};

    const int srow = lane >> 3;                 // 0..7
    const int sseg = (lane & 7) ^ srow;         // logical k-seg for this lane
    const unsigned short* gA0 = A + (size_t)(bm * 128 + wave * 8 + srow) * K + sseg * 8;
    const unsigned short* gB0 = B + (size_t)(bn * 128 + wave * 8 + srow) * K + sseg * 8;
    const int ldsbase = (wave * 8) * 64;

    const int lm = lane & 15, q = lane >> 4;
    const int sxa = (wm * 64 + lm) * 64;        // A row base for this lane
    const int sxb = (wn * 64 + lm) * 64;
    const int lmx = lm & 7;

    for (int k0 = 0; k0 < K; k0 += 64) {
        #pragma unroll
        for (int j = 0; j < 4; j++) {
            async_copy16(gA0 + k0 + (size_t)(j * 32) * K, &lds_a[j * 32 * 64 + ldsbase]);
            async_copy16(gB0 + k0 + (size_t)(j * 32) * K, &lds_b[j * 32 * 64 + ldsbase]);
        }
        __syncthreads();

        #pragma unroll
        for (int ks = 0; ks < 2; ks++) {
            const int segp = ((ks * 4 + q) ^ lmx) * 8;
            bf16x8 af[4], bfr[4];
            #pragma unroll
            for (int i = 0; i < 4; i++)
                af[i] = *(const bf16x8*)&lds_a[sxa + i * 16 * 64 + segp];
            #pragma unroll
            for (int j = 0; j < 4; j++)
                bfr[j] = *(const bf16x8*)&lds_b[sxb + j * 16 * 64 + segp];
            #pragma unroll
            for (int i = 0; i < 4; i++)
                #pragma unroll
                for (int j = 0; j < 4; j++)
                    acc[i][j] = __builtin_amdgcn_mfma_f32_16x16x32_bf16(af[i], bfr[j], acc[i][j], 0, 0, 0);
        }
        __syncthreads();
    }

    const int row0 = bm * 128 + wm * 64;
    const int col0 = bn * 128 + wn * 64;
    const int lq = (lane >> 4) * 4;
    #pragma unroll
    for (int i = 0; i < 4; i++) {
        #pragma unroll
        for (int j = 0; j < 4; j++) {
            #pragma unroll
            for (int r = 0; r < 4; r++) {
                int gr = row0 + i * 16 + lq + r;
                int gc = col0 + j * 16 + lm;
                float v = acc[i][j][r];
                if (EPI == 0) {
                    Cb[(size_t)gr * N + gc] = f2b(v);
                } else {
                    size_t idx = (size_t)gr * 1024 + gc;
                    Cf[idx] = xres[idx] + v * ls[gc];
                }
            }
        }
    }
}

// ---------- 4. conv + silu + dt ----------
__global__ __launch_bounds__(256)
void conv_dt_kernel(const unsigned short* __restrict__ zx,
                    const float* __restrict__ conv_w, const float* __restrict__ conv_b,
                    const float* __restrict__ dt_bias,
                    unsigned short* __restrict__ xbc_out,
                    float* __restrict__ dt_out) {
    int bl = blockIdx.x;
    int b = bl >> 11, l = bl & 2047;
    for (int c = threadIdx.x; c < CONV_DIM; c += 256) {
        float acc = conv_b[c];
        #pragma unroll
        for (int k = 0; k < 4; k++) {
            int t = l - 3 + k;
            if (t >= 0) {
                float xv = b2f(zx[(size_t)(b * SEQLEN + t) * NPAD + D_INNER + c]);
                acc += xv * conv_w[c * 4 + k];
            }
        }
        float s = acc / (1.f + __expf(-acc));
        xbc_out[(size_t)bl * CONV_DIM + c] = f2b(s);
    }
    if (threadIdx.x < NHEADS) {
        int h = threadIdx.x;
        float raw = b2f(zx[(size_t)bl * NPAD + D_INNER + CONV_DIM + h]) + dt_bias[h];
        float dtv = (raw > 20.f) ? raw : log1pf(__expf(raw));
        dt_out[(size_t)bl * NHEADS + h] = dtv;
    }
}

// ---------- 5a. chunk-local state: h_local = (B.w)^T X, plus chunk decay product ----------
__global__ __launch_bounds__(256)
void ssd_hcomp(const unsigned short* __restrict__ xbc, const float* __restrict__ dtb,
               const float* __restrict__ A_log,
               float* __restrict__ hbuf, float* __restrict__ pbuf) {
    __shared__ unsigned short sB[64 * 32];
    __shared__ unsigned short sXT[64 * 72];
    __shared__ unsigned short sBwT[16 * 72];
    __shared__ float sdt[64], scd[64];

    const int blk = blockIdx.x;
    const int c  = blk & 31;
    const int h  = (blk >> 5) & 31;
    const int b  = blk >> 10;
    const int bh = blk >> 5;
    const int row0 = b * SEQLEN + c * QCHUNK;

    const int t    = threadIdx.x;
    const int w    = t >> 6;
    const int lane = t & 63;
    const int lm   = lane & 15;
    const int lq8  = (lane >> 4) * 8;
    const int lq4  = (lane >> 4) * 4;
    const float Ah = -__expf(A_log[h]);

    {
        int s = t >> 2, qq = t & 3;
        const size_t grow = (size_t)(row0 + s) * CONV_DIM;
        if (qq < 2) {
            int4 v = *(const int4*)&xbc[grow + D_INNER + qq * 8];
            *(int4*)(sB + s * 32 + qq * 8) = v;
            *(int4*)(sB + s * 32 + 16 + qq * 8) = (int4){0, 0, 0, 0};
        }
        {
            int p0 = qq * 16;
            union { int4 v; unsigned short u[8]; } xa, xb;
            xa.v = *(const int4*)&xbc[grow + h * 64 + p0];
            xb.v = *(const int4*)&xbc[grow + h * 64 + p0 + 8];
            #pragma unroll
            for (int i = 0; i < 8; i++) sXT[(p0 + i) * 72 + s]     = xa.u[i];
            #pragma unroll
            for (int i = 0; i < 8; i++) sXT[(p0 + 8 + i) * 72 + s] = xb.u[i];
        }
    }
    if (t < 64) {
        float dtv = dtb[(size_t)(row0 + t) * NHEADS + h];
        float v = dtv;
        #pragma unroll
        for (int o = 1; o < 64; o <<= 1) {
            float u = __shfl_up(v, o, 64);
            if (t >= o) v += u;
        }
        sdt[t] = dtv;
        scd[t] = v;
        if (t == 63) pbuf[bh * NCHUNK + c] = __expf(Ah * v);
    }
    __syncthreads();

    {   // Bw^T [n][s] = B[s][n] * dt[s] * exp(A*(cd[63]-cd[s]))
        int n = t & 15, s0 = (t >> 4) * 4;
        float cdl = scd[63];
        #pragma unroll
        for (int i = 0; i < 4; i++) {
            int s_ = s0 + i;
            float wgt = sdt[s_] * __expf(Ah * (cdl - scd[s_]));
            sBwT[n * 72 + s_] = f2b(b2f(sB[s_ * 32 + n]) * wgt);
        }
    }
    __syncthreads();

    f32x4 hacc = (f32x4){0.f, 0.f, 0.f, 0.f};
    #pragma unroll
    for (int ks = 0; ks < 2; ks++) {
        bf16x8 af = *(const bf16x8*)&sBwT[lm * 72 + ks * 32 + lq8];
        bf16x8 bf_ = *(const bf16x8*)&sXT[(w * 16 + lm) * 72 + ks * 32 + lq8];
        hacc = __builtin_amdgcn_mfma_f32_16x16x32_bf16(af, bf_, hacc, 0, 0, 0);
    }
    #pragma unroll
    for (int r = 0; r < 4; r++)
        hbuf[(size_t)(bh * NCHUNK + c) * 1024 + (lq4 + r) * 64 + (w * 16 + lm)] = hacc[r];
}

// ---------- 5b. inter-chunk state scan (in-place: h_local -> h_in) ----------
__global__ __launch_bounds__(1024)
void ssd_state_scan(float* __restrict__ hbuf, const float* __restrict__ pbuf) {
    int bh = blockIdx.x;
    int t = threadIdx.x;
    __shared__ float sP[NCHUNK];
    if (t < NCHUNK) sP[t] = pbuf[bh * NCHUNK + t];
    __syncthreads();
    float carry = 0.f;
    size_t base = (size_t)bh * NCHUNK * 1024 + t;
    #pragma unroll 4
    for (int c = 0; c < NCHUNK; c++) {
        float v = hbuf[base + (size_t)c * 1024];
        hbuf[base + (size_t)c * 1024] = carry;
        carry = v + sP[c] * carry;
    }
}

// ---------- 5c. fused y: y = M.X + D*x + scale*(C.h_in), single write ----------
__global__ __launch_bounds__(256)
void ssd_yfused(const unsigned short* __restrict__ xbc, const float* __restrict__ dtb,
                const float* __restrict__ A_log, const float* __restrict__ D_param,
                const float* __restrict__ hbuf, unsigned short* __restrict__ y) {
    __shared__ unsigned short sB[64 * 32];
    __shared__ unsigned short sC[64 * 32];
    __shared__ unsigned short sXT[64 * 72];
    __shared__ unsigned short sM[64 * 72];
    __shared__ unsigned short sHT[64 * 40];
    __shared__ float sdt[64], scd[64], sSc[64];

    const int blk = blockIdx.x;
    const int c  = blk & 31;
    const int h  = (blk >> 5) & 31;
    const int b  = blk >> 10;
    const int bh = blk >> 5;
    const int row0 = b * SEQLEN + c * QCHUNK;

    const int t    = threadIdx.x;
    const int w    = t >> 6;
    const int lane = t & 63;
    const int lm   = lane & 15;
    const int lq8  = (lane >> 4) * 8;
    const int lq4  = (lane >> 4) * 4;
    const float Ah = -__expf(A_log[h]);

    {   // B, C, X loads
        int s = t >> 2, qq = t & 3;
        const size_t grow = (size_t)(row0 + s) * CONV_DIM;
        {
            union { int4 v; unsigned short u[8]; } bc;
            bc.v = *(const int4*)&xbc[grow + D_INNER + (qq >> 1) * 16 + (qq & 1) * 8];
            unsigned short* dst = (qq < 2 ? sB : sC) + s * 32 + (qq & 1) * 8;
            *(int4*)dst = bc.v;
            *(int4*)(dst + 16) = (int4){0, 0, 0, 0};
        }
        {
            int p0 = qq * 16;
            union { int4 v; unsigned short u[8]; } xa, xb;
            xa.v = *(const int4*)&xbc[grow + h * 64 + p0];
            xb.v = *(const int4*)&xbc[grow + h * 64 + p0 + 8];
            #pragma unroll
            for (int i = 0; i < 8; i++) sXT[(p0 + i) * 72 + s]     = xa.u[i];
            #pragma unroll
            for (int i = 0; i < 8; i++) sXT[(p0 + 8 + i) * 72 + s] = xb.u[i];
        }
    }
    {   // h_in -> sHT [p][n] bf16 (coalesced read of 4 consecutive floats)
        size_t hb = (size_t)(bh * NCHUNK + c) * 1024 + (size_t)t * 4;
        float4 hv = *(const float4*)&hbuf[hb];
        int n = t >> 4;
        int p0 = (t * 4) & 63;
        sHT[(p0 + 0) * 40 + n] = f2b(hv.x);
        sHT[(p0 + 1) * 40 + n] = f2b(hv.y);
        sHT[(p0 + 2) * 40 + n] = f2b(hv.z);
        sHT[(p0 + 3) * 40 + n] = f2b(hv.w);
    }
    if (t < 64) {   // zero-pad sHT cols 16..31 (row stride 80B is 16B-aligned)
        *(int4*)&sHT[t * 40 + 16] = (int4){0, 0, 0, 0};
        *(int4*)&sHT[t * 40 + 24] = (int4){0, 0, 0, 0};
    }
    else if (t >= 64 && t < 128) {   // dt + prefix on wave 1
        int tt = t - 64;
        float dtv = dtb[(size_t)(row0 + tt) * NHEADS + h];
        float v = dtv;
        #pragma unroll
        for (int o = 1; o < 64; o <<= 1) {
            float u = __shfl_up(v, o, 64);
            if (tt >= o) v += u;
        }
        sdt[tt] = dtv;
        scd[tt] = v;
        sSc[tt] = __expf(Ah * v);
    }
    __syncthreads();

    // S = C * B^T (lower-triangular blocks only)
    f32x4 sacc[4];
    {
        bf16x8 cfrag = *(const bf16x8*)&sC[(w * 16 + lm) * 32 + lq8];
        #pragma unroll
        for (int sb = 0; sb < 4; sb++) {
            if (sb <= w) {
                bf16x8 bfrag = *(const bf16x8*)&sB[(sb * 16 + lm) * 32 + lq8];
                sacc[sb] = __builtin_amdgcn_mfma_f32_16x16x32_bf16(
                    cfrag, bfrag, (f32x4){0.f, 0.f, 0.f, 0.f}, 0, 0, 0);
            }
        }
    }
    // M[t][s] (wave-local rows; no extra barrier needed before use)
    #pragma unroll
    for (int sb = 0; sb < 4; sb++) {
        int sp = sb * 16 + lm;
        if (sb > w) {
            #pragma unroll
            for (int r = 0; r < 4; r++) sM[(w * 16 + lq4 + r) * 72 + sp] = 0;
        } else {
            float dts = sdt[sp], cds = scd[sp];
            #pragma unroll
            for (int r = 0; r < 4; r++) {
                int tp = w * 16 + lq4 + r;
                float m = 0.f;
                if (sb < w || sp <= tp)
                    m = sacc[sb][r] * dts * __expf(Ah * (scd[tp] - cds));
                sM[tp * 72 + sp] = f2b(m);
            }
        }
    }

    // Y1 = M * X
    f32x4 yacc[4];
    #pragma unroll
    for (int pb = 0; pb < 4; pb++) yacc[pb] = (f32x4){0.f, 0.f, 0.f, 0.f};
    #pragma unroll
    for (int ks = 0; ks < 2; ks++) {
        if (ks == 1 && w < 2) continue;
        bf16x8 af = *(const bf16x8*)&sM[(w * 16 + lm) * 72 + ks * 32 + lq8];
        #pragma unroll
        for (int pb = 0; pb < 4; pb++) {
            bf16x8 bf_ = *(const bf16x8*)&sXT[(pb * 16 + lm) * 72 + ks * 32 + lq8];
            yacc[pb] = __builtin_amdgcn_mfma_f32_16x16x32_bf16(af, bf_, yacc[pb], 0, 0, 0);
        }
    }
    // Y2 = C * h_in^T
    f32x4 acc2[4];
    {
        bf16x8 cf2 = *(const bf16x8*)&sC[(w * 16 + lm) * 32 + lq8];
        #pragma unroll
        for (int pb = 0; pb < 4; pb++) {
            bf16x8 hf = *(const bf16x8*)&sHT[(pb * 16 + lm) * 40 + lq8];
            acc2[pb] = __builtin_amdgcn_mfma_f32_16x16x32_bf16(
                cf2, hf, (f32x4){0.f, 0.f, 0.f, 0.f}, 0, 0, 0);
        }
    }

    // epilogue: single y write
    const float Dh = D_param[h];
    #pragma unroll
    for (int pb = 0; pb < 4; pb++) {
        #pragma unroll
        for (int r = 0; r < 4; r++) {
            int tp = w * 16 + lq4 + r;
            int pp = pb * 16 + lm;
            float xv = b2f(sXT[pp * 72 + tp]);
            float val = yacc[pb][r] + sSc[tp] * acc2[pb][r] + Dh * xv;
            y[(size_t)(row0 + tp) * D_INNER + h * 64 + pp] = f2b(val);
        }
    }
}

// ---------- 6. gated RMSNorm ----------
__global__ __launch_bounds__(256)
void norm_kernel(const unsigned short* __restrict__ y, const unsigned short* __restrict__ zx,
                 const float* __restrict__ norm_w, unsigned short* __restrict__ yn) {
    int row = blockIdx.x;
    int tid = threadIdx.x;
    int base = tid * 8;
    const unsigned short* yr = &y[(size_t)row * D_INNER];
    const unsigned short* zr = &zx[(size_t)row * NPAD];
    ushort4 ya = *(const ushort4*)&yr[base];
    ushort4 yb = *(const ushort4*)&yr[base + 4];
    ushort4 za = *(const ushort4*)&zr[base];
    ushort4 zb = *(const ushort4*)&zr[base + 4];
    float yv[8] = { b2f(ya.x), b2f(ya.y), b2f(ya.z), b2f(ya.w),
                    b2f(yb.x), b2f(yb.y), b2f(yb.z), b2f(yb.w) };
    float zv[8] = { b2f(za.x), b2f(za.y), b2f(za.z), b2f(za.w),
                    b2f(zb.x), b2f(zb.y), b2f(zb.z), b2f(zb.w) };
    float v[8]; float ss = 0.f;
    #pragma unroll
    for (int k = 0; k < 8; k++) {
        float z = zv[k];
        float s = z / (1.f + __expf(-z));
        v[k] = yv[k] * s;
        ss += v[k] * v[k];
    }
    #pragma unroll
    for (int o = 32; o > 0; o >>= 1) ss += __shfl_xor(ss, o, 64);
    __shared__ float sred[4];
    if ((tid & 63) == 0) sred[tid >> 6] = ss;
    __syncthreads();
    float total = sred[0] + sred[1] + sred[2] + sred[3];
    float scale = rsqrtf(total * (1.f / D_INNER) + 1e-5f);
    ushort4 oa, ob;
    oa.x = f2b(v[0] * scale * norm_w[base + 0]);
    oa.y = f2b(v[1] * scale * norm_w[base + 1]);
    oa.z = f2b(v[2] * scale * norm_w[base + 2]);
    oa.w = f2b(v[3] * scale * norm_w[base + 3]);
    ob.x = f2b(v[4] * scale * norm_w[base + 4]);
    ob.y = f2b(v[5] * scale * norm_w[base + 5]);
    ob.z = f2b(v[6] * scale * norm_w[base + 6]);
    ob.w = f2b(v[7] * scale * norm_w[base + 7]);
    unsigned short* out = &yn[(size_t)row * D_INNER];
    *(ushort4*)&out[base] = oa;
    *(ushort4*)&out[base + 4] = ob;
}

// ---------- launcher ----------
extern "C" void kernel_launch(void* const* d_in, const int* in_sizes, int n_in,
                              void* d_out, int out_size, void* d_ws, size_t ws_size,
                              hipStream_t stream) {
    const float* x        = (const float*)d_in[0];
    const float* W_in     = (const float*)d_in[1];
    const float* conv_w   = (const float*)d_in[2];
    const float* conv_b   = (const float*)d_in[3];
    const float* dt_bias  = (const float*)d_in[4];
    const float* A_log    = (const float*)d_in[5];
    const float* D_param  = (const float*)d_in[6];
    const float* norm_w   = (const float*)d_in[7];
    const float* W_out    = (const float*)d_in[8];
    const float* ls       = (const float*)d_in[9];
    float* out = (float*)d_out;

    char* ws = (char*)d_ws;
    size_t off = 0;
    unsigned short* x_bf  = (unsigned short*)(ws + off); off += (size_t)MROWS * D_MODEL * 2;   // reused as hbuf
    unsigned short* winT  = (unsigned short*)(ws + off); off += (size_t)NPAD * D_MODEL * 2;
    unsigned short* woutT = (unsigned short*)(ws + off); off += (size_t)D_MODEL * D_INNER * 2;
    unsigned short* zx    = (unsigned short*)(ws + off); off += (size_t)MROWS * NPAD * 2;
    unsigned short* xbc   = (unsigned short*)(ws + off); off += (size_t)MROWS * CONV_DIM * 2;
    float*          dtb   = (float*)(ws + off);          off += (size_t)MROWS * NHEADS * 4;
    float*          pbuf  = (float*)(ws + off);          off += (size_t)BATCH * NHEADS * NCHUNK * 4;
    unsigned short* yb    = (unsigned short*)(ws + off); off += (size_t)MROWS * D_INNER * 2;
    float* hbuf = (float*)x_bf;   // x_bf dead after GEMM1; sizes match (16,777,216 B)

    cast_f32_bf16<<<(MROWS * D_MODEL) / 1024, 256, 0, stream>>>(x, x_bf, MROWS * D_MODEL);
    transpose_cast<<<dim3(NPAD / 64, D_MODEL / 64), 256, 0, stream>>>(W_in, winT, D_MODEL, D_IN_PROJ);
    transpose_cast<<<dim3(D_MODEL / 64, D_INNER / 64), 256, 0, stream>>>(W_out, woutT, D_INNER, D_MODEL);
    gemm_bf16<0><<<dim3(NPAD / 128, MROWS / 128), 256, 0, stream>>>(
        x_bf, winT, D_MODEL, NPAD, zx, nullptr, nullptr, nullptr);
    conv_dt_kernel<<<MROWS, 256, 0, stream>>>(zx, conv_w, conv_b, dt_bias, xbc, dtb);
    ssd_hcomp<<<BATCH * NHEADS * NCHUNK, 256, 0, stream>>>(xbc, dtb, A_log, hbuf, pbuf);
    ssd_state_scan<<<BATCH * NHEADS, 1024, 0, stream>>>(hbuf, pbuf);
    ssd_yfused<<<BATCH * NHEADS * NCHUNK, 256, 0, stream>>>(xbc, dtb, A_log, D_param, hbuf, yb);
    norm_kernel<<<MROWS, 256, 0, stream>>>(yb, zx, norm_w, yb);
    gemm_bf16<1><<<dim3(D_MODEL / 128, MROWS / 128), 256, 0, stream>>>(
        yb, woutT, D_INNER, D_MODEL, nullptr, out, x, ls);
}

// Round 4
// 385.577 us; speedup vs baseline: 2.3702x; 1.0553x over previous
//
#include <hip/hip_runtime.h>
#include <hip/hip_bf16.h>

// ---------- constants ----------
#define D_MODEL   1024
#define D_STATE   16
#define D_CONV    4
#define HEADDIM   64
#define NHEADS    32
#define D_INNER   2048
#define CONV_DIM  2080           // D_INNER + 2*D_STATE
#define D_IN_PROJ 4160           // 2*D_INNER + 2*D_STATE + NHEADS
#define NPAD      4224           // D_IN_PROJ padded to x128
#define BATCH     4
#define SEQLEN    2048
#define MROWS     (BATCH*SEQLEN) // 8192
#define QCHUNK    64
#define NCHUNK    (SEQLEN/QCHUNK) // 32

// ---------- helpers ----------
__device__ __forceinline__ unsigned short f2b(float f) {
    union { float f; unsigned int u; } v; v.f = f;
    unsigned int r = (v.u + 0x7FFFu + ((v.u >> 16) & 1u)) >> 16;
    return (unsigned short)r;
}
__device__ __forceinline__ float b2f(unsigned short h) {
    union { unsigned int u; float f; } v; v.u = ((unsigned int)h) << 16;
    return v.f;
}

typedef __attribute__((ext_vector_type(8))) short bf16x8;
typedef __attribute__((ext_vector_type(4))) float f32x4;

__device__ __forceinline__ void async_copy16(const unsigned short* g, unsigned short* l) {
    __builtin_amdgcn_global_load_lds(
        (const __attribute__((address_space(1))) void*)g,
        (__attribute__((address_space(3))) void*)l, 16, 0, 0);
}

// ---------- 1. cast fp32 -> bf16 ----------
__global__ void cast_f32_bf16(const float* __restrict__ in, unsigned short* __restrict__ out, int n) {
    int i = (blockIdx.x * blockDim.x + threadIdx.x) * 4;
    if (i >= n) return;
    float4 v = *(const float4*)&in[i];
    ushort4 o;
    o.x = f2b(v.x); o.y = f2b(v.y); o.z = f2b(v.z); o.w = f2b(v.w);
    *(ushort4*)&out[i] = o;
}

// ---------- 2. transpose + cast (+ optional per-K scale): W[K][N] -> WT[Np][K] bf16 ----------
__global__ void transpose_cast(const float* __restrict__ W, unsigned short* __restrict__ WT,
                               int K, int N, const float* __restrict__ kscale) {
    __shared__ float tile[64][65];
    int n0 = blockIdx.x * 64, k0 = blockIdx.y * 64;
    int tx = threadIdx.x & 63, ty = threadIdx.x >> 6;
    #pragma unroll
    for (int i = 0; i < 16; i++) {
        int r = ty * 16 + i;
        int n = n0 + tx;
        float v = (n < N) ? W[(size_t)(k0 + r) * N + n] : 0.f;
        tile[r][tx] = v;
    }
    __syncthreads();
    float ks = kscale ? kscale[k0 + tx] : 1.f;
    #pragma unroll
    for (int i = 0; i < 16; i++) {
        int r = ty * 16 + i;
        WT[(size_t)(n0 + r) * K + k0 + tx] = f2b(tile[tx][r] * ks);
    }
}

// ---------- 3. bf16 MFMA GEMM, BK=64, XOR-swizzled LDS, XCD-aware tile remap ----------
// 1-D grid of (N/128)*64 blocks.  bid&7 ~ XCD (round-robin heuristic): each XCD
// owns an 8-row bm band (A stays L2-resident, 2 MB) and sweeps bn with 8-step
// B-strip reuse.  LDS k-seg XOR swizzle keeps ds_read_b128 conflict-free.
template <int EPI>
__global__ __launch_bounds__(256)
void gemm_bf16(const unsigned short* __restrict__ A, const unsigned short* __restrict__ B,
               int K, int N, unsigned short* __restrict__ Cb,
               float* __restrict__ Cf, const float* __restrict__ xres,
               const float* __restrict__ ls, const float* __restrict__ rs) {
    __shared__ unsigned short lds_a[128 * 64];
    __shared__ unsigned short lds_b[128 * 64];
    const int tid  = threadIdx.x;
    const int wave = tid >> 6;
    const int lane = tid & 63;
    const int bid = blockIdx.x;
    const int xcd = bid & 7, g = bid >> 3;
    const int bm = xcd * 8 + (g & 7);
    const int bn = g >> 3;
    const int wm = wave >> 1, wn = wave & 1;

    f32x4 acc[4][4];
    #pragma unroll
    for (int i = 0; i < 4; i++)
        #pragma unroll
        for (int j = 0; j < 4; j++) acc[i][j] = (f32x4){0.f, 0.f, 0.f, 0.f};

    const int srow = lane >> 3;                 // 0..7
    const int sseg = (lane & 7) ^ srow;         // logical k-seg for this lane
    const unsigned short* gA0 = A + (size_t)(bm * 128 + wave * 8 + srow) * K + sseg * 8;
    const unsigned short* gB0 = B + (size_t)(bn * 128 + wave * 8 + srow) * K + sseg * 8;
    const int ldsbase = (wave * 8) * 64;

    const int lm = lane & 15, q = lane >> 4;
    const int sxa = (wm * 64 + lm) * 64;
    const int sxb = (wn * 64 + lm) * 64;
    const int lmx = lm & 7;

    for (int k0 = 0; k0 < K; k0 += 64) {
        #pragma unroll
        for (int j = 0; j < 4; j++) {
            async_copy16(gA0 + k0 + (size_t)(j * 32) * K, &lds_a[j * 32 * 64 + ldsbase]);
            async_copy16(gB0 + k0 + (size_t)(j * 32) * K, &lds_b[j * 32 * 64 + ldsbase]);
        }
        __syncthreads();

        #pragma unroll
        for (int ks = 0; ks < 2; ks++) {
            const int segp = ((ks * 4 + q) ^ lmx) * 8;
            bf16x8 af[4], bfr[4];
            #pragma unroll
            for (int i = 0; i < 4; i++)
                af[i] = *(const bf16x8*)&lds_a[sxa + i * 16 * 64 + segp];
            #pragma unroll
            for (int j = 0; j < 4; j++)
                bfr[j] = *(const bf16x8*)&lds_b[sxb + j * 16 * 64 + segp];
            #pragma unroll
            for (int i = 0; i < 4; i++)
                #pragma unroll
                for (int j = 0; j < 4; j++)
                    acc[i][j] = __builtin_amdgcn_mfma_f32_16x16x32_bf16(af[i], bfr[j], acc[i][j], 0, 0, 0);
        }
        __syncthreads();
    }

    const int row0 = bm * 128 + wm * 64;
    const int col0 = bn * 128 + wn * 64;
    const int lq = (lane >> 4) * 4;
    #pragma unroll
    for (int i = 0; i < 4; i++) {
        #pragma unroll
        for (int j = 0; j < 4; j++) {
            #pragma unroll
            for (int r = 0; r < 4; r++) {
                int gr = row0 + i * 16 + lq + r;
                int gc = col0 + j * 16 + lm;
                float v = acc[i][j][r];
                if (EPI == 0) {
                    Cb[(size_t)gr * N + gc] = f2b(v);
                } else {
                    size_t idx = (size_t)gr * 1024 + gc;
                    Cf[idx] = xres[idx] + v * ls[gc] * rs[gr];
                }
            }
        }
    }
}

// ---------- 4. conv + silu + dt ----------
__global__ __launch_bounds__(256)
void conv_dt_kernel(const unsigned short* __restrict__ zx,
                    const float* __restrict__ conv_w, const float* __restrict__ conv_b,
                    const float* __restrict__ dt_bias,
                    unsigned short* __restrict__ xbc_out,
                    float* __restrict__ dt_out) {
    int bl = blockIdx.x;
    int b = bl >> 11, l = bl & 2047;
    for (int c = threadIdx.x; c < CONV_DIM; c += 256) {
        float acc = conv_b[c];
        #pragma unroll
        for (int k = 0; k < 4; k++) {
            int t = l - 3 + k;
            if (t >= 0) {
                float xv = b2f(zx[(size_t)(b * SEQLEN + t) * NPAD + D_INNER + c]);
                acc += xv * conv_w[c * 4 + k];
            }
        }
        float s = acc / (1.f + __expf(-acc));
        xbc_out[(size_t)bl * CONV_DIM + c] = f2b(s);
    }
    if (threadIdx.x < NHEADS) {
        int h = threadIdx.x;
        float raw = b2f(zx[(size_t)bl * NPAD + D_INNER + CONV_DIM + h]) + dt_bias[h];
        float dtv = (raw > 20.f) ? raw : log1pf(__expf(raw));
        dt_out[(size_t)bl * NHEADS + h] = dtv;
    }
}

// ---------- 5a. chunk-local state: h_local = (B.w)^T X, plus chunk decay product ----------
__global__ __launch_bounds__(256)
void ssd_hcomp(const unsigned short* __restrict__ xbc, const float* __restrict__ dtb,
               const float* __restrict__ A_log,
               float* __restrict__ hbuf, float* __restrict__ pbuf) {
    __shared__ unsigned short sB[64 * 32];
    __shared__ unsigned short sXT[64 * 72];
    __shared__ unsigned short sBwT[16 * 72];
    __shared__ float sdt[64], scd[64];

    const int blk = blockIdx.x;
    const int c  = blk & 31;
    const int h  = (blk >> 5) & 31;
    const int b  = blk >> 10;
    const int bh = blk >> 5;
    const int row0 = b * SEQLEN + c * QCHUNK;

    const int t    = threadIdx.x;
    const int w    = t >> 6;
    const int lane = t & 63;
    const int lm   = lane & 15;
    const int lq8  = (lane >> 4) * 8;
    const int lq4  = (lane >> 4) * 4;
    const float Ah = -__expf(A_log[h]);

    {
        int s = t >> 2, qq = t & 3;
        const size_t grow = (size_t)(row0 + s) * CONV_DIM;
        if (qq < 2) {
            int4 v = *(const int4*)&xbc[grow + D_INNER + qq * 8];
            *(int4*)(sB + s * 32 + qq * 8) = v;
            *(int4*)(sB + s * 32 + 16 + qq * 8) = (int4){0, 0, 0, 0};
        }
        {
            int p0 = qq * 16;
            union { int4 v; unsigned short u[8]; } xa, xb;
            xa.v = *(const int4*)&xbc[grow + h * 64 + p0];
            xb.v = *(const int4*)&xbc[grow + h * 64 + p0 + 8];
            #pragma unroll
            for (int i = 0; i < 8; i++) sXT[(p0 + i) * 72 + s]     = xa.u[i];
            #pragma unroll
            for (int i = 0; i < 8; i++) sXT[(p0 + 8 + i) * 72 + s] = xb.u[i];
        }
    }
    if (t < 64) {
        float dtv = dtb[(size_t)(row0 + t) * NHEADS + h];
        float v = dtv;
        #pragma unroll
        for (int o = 1; o < 64; o <<= 1) {
            float u = __shfl_up(v, o, 64);
            if (t >= o) v += u;
        }
        sdt[t] = dtv;
        scd[t] = v;
        if (t == 63) pbuf[bh * NCHUNK + c] = __expf(Ah * v);
    }
    __syncthreads();

    {   // Bw^T [n][s] = B[s][n] * dt[s] * exp(A*(cd[63]-cd[s]))
        int n = t & 15, s0 = (t >> 4) * 4;
        float cdl = scd[63];
        #pragma unroll
        for (int i = 0; i < 4; i++) {
            int s_ = s0 + i;
            float wgt = sdt[s_] * __expf(Ah * (cdl - scd[s_]));
            sBwT[n * 72 + s_] = f2b(b2f(sB[s_ * 32 + n]) * wgt);
        }
    }
    __syncthreads();

    f32x4 hacc = (f32x4){0.f, 0.f, 0.f, 0.f};
    #pragma unroll
    for (int ks = 0; ks < 2; ks++) {
        bf16x8 af = *(const bf16x8*)&sBwT[lm * 72 + ks * 32 + lq8];
        bf16x8 bf_ = *(const bf16x8*)&sXT[(w * 16 + lm) * 72 + ks * 32 + lq8];
        hacc = __builtin_amdgcn_mfma_f32_16x16x32_bf16(af, bf_, hacc, 0, 0, 0);
    }
    #pragma unroll
    for (int r = 0; r < 4; r++)
        hbuf[(size_t)(bh * NCHUNK + c) * 1024 + (lq4 + r) * 64 + (w * 16 + lm)] = hacc[r];
}

// ---------- 5b. inter-chunk state scan (in-place: h_local -> h_in) ----------
__global__ __launch_bounds__(1024)
void ssd_state_scan(float* __restrict__ hbuf, const float* __restrict__ pbuf) {
    int bh = blockIdx.x;
    int t = threadIdx.x;
    __shared__ float sP[NCHUNK];
    if (t < NCHUNK) sP[t] = pbuf[bh * NCHUNK + t];
    __syncthreads();
    float carry = 0.f;
    size_t base = (size_t)bh * NCHUNK * 1024 + t;
    #pragma unroll 4
    for (int c = 0; c < NCHUNK; c++) {
        float v = hbuf[base + (size_t)c * 1024];
        hbuf[base + (size_t)c * 1024] = carry;
        carry = v + sP[c] * carry;
    }
}

// ---------- 5c. fused y: yg = (M.X + D*x + scale*(C.h_in)) * silu(z), + row ssq partials ----------
__global__ __launch_bounds__(256)
void ssd_yfused(const unsigned short* __restrict__ xbc, const float* __restrict__ dtb,
                const float* __restrict__ A_log, const float* __restrict__ D_param,
                const float* __restrict__ hbuf, const unsigned short* __restrict__ zx,
                unsigned short* __restrict__ y, float* __restrict__ ssq) {
    __shared__ unsigned short sB[64 * 32];
    __shared__ unsigned short sC[64 * 32];
    __shared__ unsigned short sXT[64 * 72];
    __shared__ unsigned short sM[64 * 72];
    __shared__ unsigned short sHT[64 * 40];
    __shared__ float sdt[64], scd[64], sSc[64];

    const int blk = blockIdx.x;
    const int c  = blk & 31;
    const int h  = (blk >> 5) & 31;
    const int b  = blk >> 10;
    const int bh = blk >> 5;
    const int row0 = b * SEQLEN + c * QCHUNK;

    const int t    = threadIdx.x;
    const int w    = t >> 6;
    const int lane = t & 63;
    const int lm   = lane & 15;
    const int lq8  = (lane >> 4) * 8;
    const int lq4  = (lane >> 4) * 4;
    const float Ah = -__expf(A_log[h]);

    {   // B, C, X loads
        int s = t >> 2, qq = t & 3;
        const size_t grow = (size_t)(row0 + s) * CONV_DIM;
        {
            union { int4 v; unsigned short u[8]; } bc;
            bc.v = *(const int4*)&xbc[grow + D_INNER + (qq >> 1) * 16 + (qq & 1) * 8];
            unsigned short* dst = (qq < 2 ? sB : sC) + s * 32 + (qq & 1) * 8;
            *(int4*)dst = bc.v;
            *(int4*)(dst + 16) = (int4){0, 0, 0, 0};
        }
        {
            int p0 = qq * 16;
            union { int4 v; unsigned short u[8]; } xa, xb;
            xa.v = *(const int4*)&xbc[grow + h * 64 + p0];
            xb.v = *(const int4*)&xbc[grow + h * 64 + p0 + 8];
            #pragma unroll
            for (int i = 0; i < 8; i++) sXT[(p0 + i) * 72 + s]     = xa.u[i];
            #pragma unroll
            for (int i = 0; i < 8; i++) sXT[(p0 + 8 + i) * 72 + s] = xb.u[i];
        }
    }
    {   // h_in -> sHT [p][n] bf16
        size_t hb = (size_t)(bh * NCHUNK + c) * 1024 + (size_t)t * 4;
        float4 hv = *(const float4*)&hbuf[hb];
        int n = t >> 4;
        int p0 = (t * 4) & 63;
        sHT[(p0 + 0) * 40 + n] = f2b(hv.x);
        sHT[(p0 + 1) * 40 + n] = f2b(hv.y);
        sHT[(p0 + 2) * 40 + n] = f2b(hv.z);
        sHT[(p0 + 3) * 40 + n] = f2b(hv.w);
    }
    if (t < 64) {
        *(int4*)&sHT[t * 40 + 16] = (int4){0, 0, 0, 0};
        *(int4*)&sHT[t * 40 + 24] = (int4){0, 0, 0, 0};
    }
    else if (t >= 64 && t < 128) {
        int tt = t - 64;
        float dtv = dtb[(size_t)(row0 + tt) * NHEADS + h];
        float v = dtv;
        #pragma unroll
        for (int o = 1; o < 64; o <<= 1) {
            float u = __shfl_up(v, o, 64);
            if (tt >= o) v += u;
        }
        sdt[tt] = dtv;
        scd[tt] = v;
        sSc[tt] = __expf(Ah * v);
    }
    __syncthreads();

    // S = C * B^T (lower-triangular blocks only)
    f32x4 sacc[4];
    {
        bf16x8 cfrag = *(const bf16x8*)&sC[(w * 16 + lm) * 32 + lq8];
        #pragma unroll
        for (int sb = 0; sb < 4; sb++) {
            if (sb <= w) {
                bf16x8 bfrag = *(const bf16x8*)&sB[(sb * 16 + lm) * 32 + lq8];
                sacc[sb] = __builtin_amdgcn_mfma_f32_16x16x32_bf16(
                    cfrag, bfrag, (f32x4){0.f, 0.f, 0.f, 0.f}, 0, 0, 0);
            }
        }
    }
    // M[t][s] (wave-local rows)
    #pragma unroll
    for (int sb = 0; sb < 4; sb++) {
        int sp = sb * 16 + lm;
        if (sb > w) {
            #pragma unroll
            for (int r = 0; r < 4; r++) sM[(w * 16 + lq4 + r) * 72 + sp] = 0;
        } else {
            float dts = sdt[sp], cds = scd[sp];
            #pragma unroll
            for (int r = 0; r < 4; r++) {
                int tp = w * 16 + lq4 + r;
                float m = 0.f;
                if (sb < w || sp <= tp)
                    m = sacc[sb][r] * dts * __expf(Ah * (scd[tp] - cds));
                sM[tp * 72 + sp] = f2b(m);
            }
        }
    }

    // Y1 = M * X
    f32x4 yacc[4];
    #pragma unroll
    for (int pb = 0; pb < 4; pb++) yacc[pb] = (f32x4){0.f, 0.f, 0.f, 0.f};
    #pragma unroll
    for (int ks = 0; ks < 2; ks++) {
        if (ks == 1 && w < 2) continue;
        bf16x8 af = *(const bf16x8*)&sM[(w * 16 + lm) * 72 + ks * 32 + lq8];
        #pragma unroll
        for (int pb = 0; pb < 4; pb++) {
            bf16x8 bf_ = *(const bf16x8*)&sXT[(pb * 16 + lm) * 72 + ks * 32 + lq8];
            yacc[pb] = __builtin_amdgcn_mfma_f32_16x16x32_bf16(af, bf_, yacc[pb], 0, 0, 0);
        }
    }
    // Y2 = C * h_in^T
    f32x4 acc2[4];
    {
        bf16x8 cf2 = *(const bf16x8*)&sC[(w * 16 + lm) * 32 + lq8];
        #pragma unroll
        for (int pb = 0; pb < 4; pb++) {
            bf16x8 hf = *(const bf16x8*)&sHT[(pb * 16 + lm) * 40 + lq8];
            acc2[pb] = __builtin_amdgcn_mfma_f32_16x16x32_bf16(
                cf2, hf, (f32x4){0.f, 0.f, 0.f, 0.f}, 0, 0, 0);
        }
    }

    // epilogue: gate with silu(z), single y write, per-row ssq partials
    const float Dh = D_param[h];
    #pragma unroll
    for (int r = 0; r < 4; r++) {
        const int tp = w * 16 + lq4 + r;
        const size_t zrow = (size_t)(row0 + tp) * NPAD + h * 64;
        const size_t yrow = (size_t)(row0 + tp) * D_INNER + h * 64;
        float ssr = 0.f;
        #pragma unroll
        for (int pb = 0; pb < 4; pb++) {
            int pp = pb * 16 + lm;
            float xv = b2f(sXT[pp * 72 + tp]);
            float val = yacc[pb][r] + sSc[tp] * acc2[pb][r] + Dh * xv;
            float zv = b2f(zx[zrow + pp]);
            float yg = val * (zv / (1.f + __expf(-zv)));
            ssr += yg * yg;
            y[yrow + pp] = f2b(yg);
        }
        ssr += __shfl_xor(ssr, 1, 16);
        ssr += __shfl_xor(ssr, 2, 16);
        ssr += __shfl_xor(ssr, 4, 16);
        ssr += __shfl_xor(ssr, 8, 16);
        if (lm == 0)
            ssq[(size_t)(row0 + tp) * NHEADS + h] = ssr;
    }
}

// ---------- 5d. per-row rsqrt scale ----------
__global__ __launch_bounds__(256)
void rowscale_kernel(const float* __restrict__ ssq, float* __restrict__ rs) {
    int row = blockIdx.x * 256 + threadIdx.x;
    const float4* p = (const float4*)&ssq[(size_t)row * NHEADS];
    float s = 0.f;
    #pragma unroll
    for (int i = 0; i < 8; i++) {
        float4 v = p[i];
        s += v.x + v.y + v.z + v.w;
    }
    rs[row] = rsqrtf(s * (1.f / D_INNER) + 1e-5f);
}

// ---------- launcher ----------
extern "C" void kernel_launch(void* const* d_in, const int* in_sizes, int n_in,
                              void* d_out, int out_size, void* d_ws, size_t ws_size,
                              hipStream_t stream) {
    const float* x        = (const float*)d_in[0];
    const float* W_in     = (const float*)d_in[1];
    const float* conv_w   = (const float*)d_in[2];
    const float* conv_b   = (const float*)d_in[3];
    const float* dt_bias  = (const float*)d_in[4];
    const float* A_log    = (const float*)d_in[5];
    const float* D_param  = (const float*)d_in[6];
    const float* norm_w   = (const float*)d_in[7];
    const float* W_out    = (const float*)d_in[8];
    const float* ls       = (const float*)d_in[9];
    float* out = (float*)d_out;

    char* ws = (char*)d_ws;
    size_t off = 0;
    unsigned short* x_bf  = (unsigned short*)(ws + off); off += (size_t)MROWS * D_MODEL * 2;   // reused as hbuf
    unsigned short* winT  = (unsigned short*)(ws + off); off += (size_t)NPAD * D_MODEL * 2;
    unsigned short* woutT = (unsigned short*)(ws + off); off += (size_t)D_MODEL * D_INNER * 2;
    unsigned short* zx    = (unsigned short*)(ws + off); off += (size_t)MROWS * NPAD * 2;
    unsigned short* xbc   = (unsigned short*)(ws + off); off += (size_t)MROWS * CONV_DIM * 2;
    float*          dtb   = (float*)(ws + off);          off += (size_t)MROWS * NHEADS * 4;
    float*          pbuf  = (float*)(ws + off);          off += (size_t)BATCH * NHEADS * NCHUNK * 4;
    unsigned short* yb    = (unsigned short*)(ws + off); off += (size_t)MROWS * D_INNER * 2;
    float*          ssq   = (float*)(ws + off);          off += (size_t)MROWS * NHEADS * 4;
    float*          rsb   = (float*)(ws + off);          off += (size_t)MROWS * 4;
    float* hbuf = (float*)x_bf;   // x_bf dead after GEMM1; sizes match (16,777,216 B)

    cast_f32_bf16<<<(MROWS * D_MODEL) / 1024, 256, 0, stream>>>(x, x_bf, MROWS * D_MODEL);
    transpose_cast<<<dim3(NPAD / 64, D_MODEL / 64), 256, 0, stream>>>(W_in, winT, D_MODEL, D_IN_PROJ, nullptr);
    // norm_w folded into W_out^T rows (per-K scale)
    transpose_cast<<<dim3(D_MODEL / 64, D_INNER / 64), 256, 0, stream>>>(W_out, woutT, D_INNER, D_MODEL, norm_w);
    gemm_bf16<0><<<(NPAD / 128) * 64, 256, 0, stream>>>(
        x_bf, winT, D_MODEL, NPAD, zx, nullptr, nullptr, nullptr, nullptr);
    conv_dt_kernel<<<MROWS, 256, 0, stream>>>(zx, conv_w, conv_b, dt_bias, xbc, dtb);
    ssd_hcomp<<<BATCH * NHEADS * NCHUNK, 256, 0, stream>>>(xbc, dtb, A_log, hbuf, pbuf);
    ssd_state_scan<<<BATCH * NHEADS, 1024, 0, stream>>>(hbuf, pbuf);
    ssd_yfused<<<BATCH * NHEADS * NCHUNK, 256, 0, stream>>>(
        xbc, dtb, A_log, D_param, hbuf, zx, yb, ssq);
    rowscale_kernel<<<MROWS / 256, 256, 0, stream>>>(ssq, rsb);
    gemm_bf16<1><<<(D_MODEL / 128) * 64, 256, 0, stream>>>(
        yb, woutT, D_INNER, D_MODEL, nullptr, out, x, ls, rsb);
}

// Round 5
// 351.111 us; speedup vs baseline: 2.6028x; 1.0982x over previous
//
#include <hip/hip_runtime.h>
#include <hip/hip_bf16.h>

// ---------- constants ----------
#define D_MODEL   1024
#define D_STATE   16
#define D_CONV    4
#define HEADDIM   64
#define NHEADS    32
#define D_INNER   2048
#define CONV_DIM  2080           // D_INNER + 2*D_STATE
#define D_IN_PROJ 4160           // 2*D_INNER + 2*D_STATE + NHEADS
#define NPAD      4224           // D_IN_PROJ padded to x128
#define BATCH     4
#define SEQLEN    2048
#define MROWS     (BATCH*SEQLEN) // 8192
#define QCHUNK    64
#define NCHUNK    (SEQLEN/QCHUNK) // 32
#define DT_COL    (2*D_INNER + 2*D_STATE)   // 4128: dt raw column in zx

// ---------- helpers ----------
__device__ __forceinline__ unsigned short f2b(float f) {
    union { float f; unsigned int u; } v; v.f = f;
    unsigned int r = (v.u + 0x7FFFu + ((v.u >> 16) & 1u)) >> 16;
    return (unsigned short)r;
}
__device__ __forceinline__ float b2f(unsigned short h) {
    union { unsigned int u; float f; } v; v.u = ((unsigned int)h) << 16;
    return v.f;
}

typedef __attribute__((ext_vector_type(8))) short bf16x8;
typedef __attribute__((ext_vector_type(4))) float f32x4;

__device__ __forceinline__ void async_copy16(const unsigned short* g, unsigned short* l) {
    __builtin_amdgcn_global_load_lds(
        (const __attribute__((address_space(1))) void*)g,
        (__attribute__((address_space(3))) void*)l, 16, 0, 0);
}

// ---------- 1. cast fp32 -> bf16 ----------
__global__ void cast_f32_bf16(const float* __restrict__ in, unsigned short* __restrict__ out, int n) {
    int i = (blockIdx.x * blockDim.x + threadIdx.x) * 4;
    if (i >= n) return;
    float4 v = *(const float4*)&in[i];
    ushort4 o;
    o.x = f2b(v.x); o.y = f2b(v.y); o.z = f2b(v.z); o.w = f2b(v.w);
    *(ushort4*)&out[i] = o;
}

// ---------- 2. both weight transposes in one launch ----------
// blocks [0,1056): W_in (K=1024,N=4160->Np=4224).  [1056,1568): W_out*norm_w (K=2048,N=1024).
__global__ void transpose_both(const float* __restrict__ W_in, unsigned short* __restrict__ winT,
                               const float* __restrict__ W_out, unsigned short* __restrict__ woutT,
                               const float* __restrict__ norm_w) {
    __shared__ float tile[64][65];
    int bid = blockIdx.x;
    const float* W; unsigned short* WT; const float* kscale;
    int K, N, bx, by;
    if (bid < 1056) { W = W_in;  WT = winT;  kscale = nullptr; K = 1024; N = 4160; bx = bid % 66; by = bid / 66; }
    else { bid -= 1056; W = W_out; WT = woutT; kscale = norm_w; K = 2048; N = 1024; bx = bid % 16; by = bid / 16; }
    int n0 = bx * 64, k0 = by * 64;
    int tx = threadIdx.x & 63, ty = threadIdx.x >> 6;
    #pragma unroll
    for (int i = 0; i < 16; i++) {
        int r = ty * 16 + i;
        int n = n0 + tx;
        float v = (n < N) ? W[(size_t)(k0 + r) * N + n] : 0.f;
        tile[r][tx] = v;
    }
    __syncthreads();
    float ks = kscale ? kscale[k0 + tx] : 1.f;
    #pragma unroll
    for (int i = 0; i < 16; i++) {
        int r = ty * 16 + i;
        WT[(size_t)(n0 + r) * K + k0 + tx] = f2b(tile[tx][r] * ks);
    }
}

// ---------- 3. bf16 MFMA GEMM, BK=64, XOR-swizzled LDS, XCD-aware tile remap ----------
template <int EPI>
__global__ __launch_bounds__(256)
void gemm_bf16(const unsigned short* __restrict__ A, const unsigned short* __restrict__ B,
               int K, int N, unsigned short* __restrict__ Cb,
               float* __restrict__ Cf, const float* __restrict__ xres,
               const float* __restrict__ ls, const float* __restrict__ rs) {
    __shared__ unsigned short lds_a[128 * 64];
    __shared__ unsigned short lds_b[128 * 64];
    const int tid  = threadIdx.x;
    const int wave = tid >> 6;
    const int lane = tid & 63;
    const int bid = blockIdx.x;
    const int xcd = bid & 7, g = bid >> 3;
    const int bm = xcd * 8 + (g & 7);
    const int bn = g >> 3;
    const int wm = wave >> 1, wn = wave & 1;

    f32x4 acc[4][4];
    #pragma unroll
    for (int i = 0; i < 4; i++)
        #pragma unroll
        for (int j = 0; j < 4; j++) acc[i][j] = (f32x4){0.f, 0.f, 0.f, 0.f};

    const int srow = lane >> 3;
    const int sseg = (lane & 7) ^ srow;
    const unsigned short* gA0 = A + (size_t)(bm * 128 + wave * 8 + srow) * K + sseg * 8;
    const unsigned short* gB0 = B + (size_t)(bn * 128 + wave * 8 + srow) * K + sseg * 8;
    const int ldsbase = (wave * 8) * 64;

    const int lm = lane & 15, q = lane >> 4;
    const int sxa = (wm * 64 + lm) * 64;
    const int sxb = (wn * 64 + lm) * 64;
    const int lmx = lm & 7;

    for (int k0 = 0; k0 < K; k0 += 64) {
        #pragma unroll
        for (int j = 0; j < 4; j++) {
            async_copy16(gA0 + k0 + (size_t)(j * 32) * K, &lds_a[j * 32 * 64 + ldsbase]);
            async_copy16(gB0 + k0 + (size_t)(j * 32) * K, &lds_b[j * 32 * 64 + ldsbase]);
        }
        __syncthreads();

        #pragma unroll
        for (int ks = 0; ks < 2; ks++) {
            const int segp = ((ks * 4 + q) ^ lmx) * 8;
            bf16x8 af[4], bfr[4];
            #pragma unroll
            for (int i = 0; i < 4; i++)
                af[i] = *(const bf16x8*)&lds_a[sxa + i * 16 * 64 + segp];
            #pragma unroll
            for (int j = 0; j < 4; j++)
                bfr[j] = *(const bf16x8*)&lds_b[sxb + j * 16 * 64 + segp];
            #pragma unroll
            for (int i = 0; i < 4; i++)
                #pragma unroll
                for (int j = 0; j < 4; j++)
                    acc[i][j] = __builtin_amdgcn_mfma_f32_16x16x32_bf16(af[i], bfr[j], acc[i][j], 0, 0, 0);
        }
        __syncthreads();
    }

    const int row0 = bm * 128 + wm * 64;
    const int col0 = bn * 128 + wn * 64;
    const int lq = (lane >> 4) * 4;
    #pragma unroll
    for (int i = 0; i < 4; i++) {
        #pragma unroll
        for (int j = 0; j < 4; j++) {
            #pragma unroll
            for (int r = 0; r < 4; r++) {
                int gr = row0 + i * 16 + lq + r;
                int gc = col0 + j * 16 + lm;
                float v = acc[i][j][r];
                if (EPI == 0) {
                    Cb[(size_t)gr * N + gc] = f2b(v);
                } else {
                    size_t idx = (size_t)gr * 1024 + gc;
                    Cf[idx] = xres[idx] + v * ls[gc] * rs[gr];
                }
            }
        }
    }
}

// ---------- 5a. chunk-local state (conv fused): h_local = (B.w)^T X ----------
__global__ __launch_bounds__(256)
void ssd_hcomp(const unsigned short* __restrict__ zx, const float* __restrict__ dt_bias,
               const float* __restrict__ conv_w, const float* __restrict__ conv_b,
               const float* __restrict__ A_log,
               float* __restrict__ hbuf, float* __restrict__ pbuf) {
    __shared__ unsigned short sXraw[67 * 64];   // rows -3..63, X head slice
    __shared__ unsigned short sBraw[67 * 32];   // rows -3..63, B+C channels (only B used)
    __shared__ unsigned short sXT[64 * 72];     // conv(X)^T [p][s]
    __shared__ unsigned short sBwT[16 * 72];    // weighted conv(B)^T [n][s]
    __shared__ float sdt[64], scd[64];

    const int blk = blockIdx.x;
    const int c  = blk & 31;
    const int h  = (blk >> 5) & 31;
    const int b  = blk >> 10;
    const int bh = blk >> 5;
    const int row0 = b * SEQLEN + c * QCHUNK;
    const int batch0 = b * SEQLEN;

    const int t    = threadIdx.x;
    const int w    = t >> 6;
    const int lane = t & 63;
    const int lm   = lane & 15;
    const int lq8  = (lane >> 4) * 8;
    const int lq4  = (lane >> 4) * 4;
    const float Ah = -__expf(A_log[h]);

    // ---- phase 1: raw loads + dt softplus/prefix ----
    for (int i = t; i < 536; i += 256) {        // X: 67 rows x 8 segs
        int r = i >> 3, seg = i & 7;
        int gr = row0 - 3 + r;
        int4 v = (gr >= batch0) ? *(const int4*)&zx[(size_t)gr * NPAD + D_INNER + h * 64 + seg * 8]
                                : (int4){0, 0, 0, 0};
        *(int4*)&sXraw[r * 64 + seg * 8] = v;
    }
    for (int i = t; i < 268; i += 256) {        // BC: 67 rows x 4 segs
        int r = i >> 2, seg = i & 3;
        int gr = row0 - 3 + r;
        int4 v = (gr >= batch0) ? *(const int4*)&zx[(size_t)gr * NPAD + 2 * D_INNER + seg * 8]
                                : (int4){0, 0, 0, 0};
        *(int4*)&sBraw[r * 32 + seg * 8] = v;
    }
    if (t < 64) {
        float raw = b2f(zx[(size_t)(row0 + t) * NPAD + DT_COL + h]) + dt_bias[h];
        float dtv = (raw > 20.f) ? raw : log1pf(__expf(raw));
        float v = dtv;
        #pragma unroll
        for (int o = 1; o < 64; o <<= 1) {
            float u = __shfl_up(v, o, 64);
            if (t >= o) v += u;
        }
        sdt[t] = dtv;
        scd[t] = v;
        if (t == 63) pbuf[bh * NCHUNK + c] = __expf(Ah * v);
    }
    __syncthreads();

    // ---- phase 2: conv + silu ----
    {   // X: thread owns col p, 16 s values
        const int p = t & 63, sblk = (t >> 6) * 16;
        const int ch = h * 64 + p;
        const float cw0 = conv_w[ch * 4 + 0], cw1 = conv_w[ch * 4 + 1];
        const float cw2 = conv_w[ch * 4 + 2], cw3 = conv_w[ch * 4 + 3];
        const float cb = conv_b[ch];
        #pragma unroll
        for (int i = 0; i < 16; i++) {
            int s = sblk + i;
            float acc = cb + cw0 * b2f(sXraw[s * 64 + p]) + cw1 * b2f(sXraw[(s + 1) * 64 + p])
                           + cw2 * b2f(sXraw[(s + 2) * 64 + p]) + cw3 * b2f(sXraw[(s + 3) * 64 + p]);
            float sv = acc / (1.f + __expf(-acc));
            sXT[p * 72 + s] = f2b(sv);
        }
    }
    {   // B: thread owns state n, 4 s values; apply dt*decay weight directly
        const int n = t & 15, s0 = (t >> 4) * 4;
        const int ch = D_INNER + n;
        const float cw0 = conv_w[ch * 4 + 0], cw1 = conv_w[ch * 4 + 1];
        const float cw2 = conv_w[ch * 4 + 2], cw3 = conv_w[ch * 4 + 3];
        const float cb = conv_b[ch];
        const float cdl = scd[63];
        #pragma unroll
        for (int i = 0; i < 4; i++) {
            int s = s0 + i;
            float acc = cb + cw0 * b2f(sBraw[s * 32 + n]) + cw1 * b2f(sBraw[(s + 1) * 32 + n])
                           + cw2 * b2f(sBraw[(s + 2) * 32 + n]) + cw3 * b2f(sBraw[(s + 3) * 32 + n]);
            float sv = acc / (1.f + __expf(-acc));
            float wgt = sdt[s] * __expf(Ah * (cdl - scd[s]));
            sBwT[n * 72 + s] = f2b(sv * wgt);
        }
    }
    __syncthreads();

    // ---- phase 3: h_local = Bw^T X ----
    f32x4 hacc = (f32x4){0.f, 0.f, 0.f, 0.f};
    #pragma unroll
    for (int ks = 0; ks < 2; ks++) {
        bf16x8 af = *(const bf16x8*)&sBwT[lm * 72 + ks * 32 + lq8];
        bf16x8 bf_ = *(const bf16x8*)&sXT[(w * 16 + lm) * 72 + ks * 32 + lq8];
        hacc = __builtin_amdgcn_mfma_f32_16x16x32_bf16(af, bf_, hacc, 0, 0, 0);
    }
    #pragma unroll
    for (int r = 0; r < 4; r++)
        hbuf[(size_t)(bh * NCHUNK + c) * 1024 + (lq4 + r) * 64 + (w * 16 + lm)] = hacc[r];
}

// ---------- 5b. inter-chunk state scan: register-prefetched ----------
__global__ __launch_bounds__(1024)
void ssd_state_scan(float* __restrict__ hbuf, const float* __restrict__ pbuf) {
    int bh = blockIdx.x;
    int t = threadIdx.x;
    __shared__ float sP[NCHUNK];
    if (t < NCHUNK) sP[t] = pbuf[bh * NCHUNK + t];
    __syncthreads();
    size_t base = (size_t)bh * NCHUNK * 1024 + t;
    float v[NCHUNK];
    #pragma unroll
    for (int c = 0; c < NCHUNK; c++) v[c] = hbuf[base + (size_t)c * 1024];
    float carry = 0.f;
    #pragma unroll
    for (int c = 0; c < NCHUNK; c++) {
        float tmp = v[c];
        v[c] = carry;
        carry = tmp + sP[c] * carry;
    }
    #pragma unroll
    for (int c = 0; c < NCHUNK; c++) hbuf[base + (size_t)c * 1024] = v[c];
}

// ---------- 5c. fused y (conv fused): yg = (M.X + D*x + scale*(C.h_in)) * silu(z) ----------
__global__ __launch_bounds__(256)
void ssd_yfused(const unsigned short* __restrict__ zx, const float* __restrict__ dt_bias,
                const float* __restrict__ conv_w, const float* __restrict__ conv_b,
                const float* __restrict__ A_log, const float* __restrict__ D_param,
                const float* __restrict__ hbuf,
                unsigned short* __restrict__ y, float* __restrict__ ssq) {
    __shared__ unsigned short sXraw[67 * 64];
    __shared__ unsigned short sBCraw[67 * 32];
    __shared__ unsigned short sB[64 * 32];
    __shared__ unsigned short sC[64 * 32];
    __shared__ unsigned short sXT[64 * 72];
    __shared__ unsigned short sM[64 * 72];
    __shared__ unsigned short sHT[64 * 40];
    __shared__ float sdt[64], scd[64], sSc[64];

    const int blk = blockIdx.x;
    const int c  = blk & 31;
    const int h  = (blk >> 5) & 31;
    const int b  = blk >> 10;
    const int bh = blk >> 5;
    const int row0 = b * SEQLEN + c * QCHUNK;
    const int batch0 = b * SEQLEN;

    const int t    = threadIdx.x;
    const int w    = t >> 6;
    const int lane = t & 63;
    const int lm   = lane & 15;
    const int lq8  = (lane >> 4) * 8;
    const int lq4  = (lane >> 4) * 4;
    const float Ah = -__expf(A_log[h]);

    // ---- phase 1: raw loads + h_in + dt ----
    for (int i = t; i < 536; i += 256) {
        int r = i >> 3, seg = i & 7;
        int gr = row0 - 3 + r;
        int4 v = (gr >= batch0) ? *(const int4*)&zx[(size_t)gr * NPAD + D_INNER + h * 64 + seg * 8]
                                : (int4){0, 0, 0, 0};
        *(int4*)&sXraw[r * 64 + seg * 8] = v;
    }
    for (int i = t; i < 268; i += 256) {
        int r = i >> 2, seg = i & 3;
        int gr = row0 - 3 + r;
        int4 v = (gr >= batch0) ? *(const int4*)&zx[(size_t)gr * NPAD + 2 * D_INNER + seg * 8]
                                : (int4){0, 0, 0, 0};
        *(int4*)&sBCraw[r * 32 + seg * 8] = v;
    }
    {   // h_in -> sHT [p][n] bf16
        size_t hb = (size_t)(bh * NCHUNK + c) * 1024 + (size_t)t * 4;
        float4 hv = *(const float4*)&hbuf[hb];
        int n = t >> 4;
        int p0 = (t * 4) & 63;
        sHT[(p0 + 0) * 40 + n] = f2b(hv.x);
        sHT[(p0 + 1) * 40 + n] = f2b(hv.y);
        sHT[(p0 + 2) * 40 + n] = f2b(hv.z);
        sHT[(p0 + 3) * 40 + n] = f2b(hv.w);
    }
    if (t < 64) {
        float raw = b2f(zx[(size_t)(row0 + t) * NPAD + DT_COL + h]) + dt_bias[h];
        float dtv = (raw > 20.f) ? raw : log1pf(__expf(raw));
        float v = dtv;
        #pragma unroll
        for (int o = 1; o < 64; o <<= 1) {
            float u = __shfl_up(v, o, 64);
            if (t >= o) v += u;
        }
        sdt[t] = dtv;
        scd[t] = v;
        sSc[t] = __expf(Ah * v);
    } else if (t < 128) {
        int tt = t - 64;
        *(int4*)&sHT[tt * 40 + 16] = (int4){0, 0, 0, 0};
        *(int4*)&sHT[tt * 40 + 24] = (int4){0, 0, 0, 0};
    }
    __syncthreads();

    // ---- phase 2: conv + silu ----
    {   // X
        const int p = t & 63, sblk = (t >> 6) * 16;
        const int ch = h * 64 + p;
        const float cw0 = conv_w[ch * 4 + 0], cw1 = conv_w[ch * 4 + 1];
        const float cw2 = conv_w[ch * 4 + 2], cw3 = conv_w[ch * 4 + 3];
        const float cb = conv_b[ch];
        #pragma unroll
        for (int i = 0; i < 16; i++) {
            int s = sblk + i;
            float acc = cb + cw0 * b2f(sXraw[s * 64 + p]) + cw1 * b2f(sXraw[(s + 1) * 64 + p])
                           + cw2 * b2f(sXraw[(s + 2) * 64 + p]) + cw3 * b2f(sXraw[(s + 3) * 64 + p]);
            float sv = acc / (1.f + __expf(-acc));
            sXT[p * 72 + s] = f2b(sv);
        }
    }
    {   // B and C: thread owns channel ch32 (0..31), 8 s values
        const int ch32 = t & 31, s0 = (t >> 5) * 8;
        const int ch = D_INNER + ch32;
        const float cw0 = conv_w[ch * 4 + 0], cw1 = conv_w[ch * 4 + 1];
        const float cw2 = conv_w[ch * 4 + 2], cw3 = conv_w[ch * 4 + 3];
        const float cb = conv_b[ch];
        unsigned short* dst = (ch32 < 16) ? &sB[ch32] : &sC[ch32 - 16];
        #pragma unroll
        for (int i = 0; i < 8; i++) {
            int s = s0 + i;
            float acc = cb + cw0 * b2f(sBCraw[s * 32 + ch32]) + cw1 * b2f(sBCraw[(s + 1) * 32 + ch32])
                           + cw2 * b2f(sBCraw[(s + 2) * 32 + ch32]) + cw3 * b2f(sBCraw[(s + 3) * 32 + ch32]);
            float sv = acc / (1.f + __expf(-acc));
            dst[s * 32] = f2b(sv);
        }
    }
    if (t < 64) {   // zero-pad B/C cols 16..31
        *(int4*)&sB[t * 32 + 16] = (int4){0, 0, 0, 0};
        *(int4*)&sB[t * 32 + 24] = (int4){0, 0, 0, 0};
        *(int4*)&sC[t * 32 + 16] = (int4){0, 0, 0, 0};
        *(int4*)&sC[t * 32 + 24] = (int4){0, 0, 0, 0};
    }
    __syncthreads();

    // ---- phase 3: S = C * B^T (lower-triangular blocks) ----
    f32x4 sacc[4];
    {
        bf16x8 cfrag = *(const bf16x8*)&sC[(w * 16 + lm) * 32 + lq8];
        #pragma unroll
        for (int sb = 0; sb < 4; sb++) {
            if (sb <= w) {
                bf16x8 bfrag = *(const bf16x8*)&sB[(sb * 16 + lm) * 32 + lq8];
                sacc[sb] = __builtin_amdgcn_mfma_f32_16x16x32_bf16(
                    cfrag, bfrag, (f32x4){0.f, 0.f, 0.f, 0.f}, 0, 0, 0);
            }
        }
    }
    // M[t][s] (wave-local rows)
    #pragma unroll
    for (int sb = 0; sb < 4; sb++) {
        int sp = sb * 16 + lm;
        if (sb > w) {
            #pragma unroll
            for (int r = 0; r < 4; r++) sM[(w * 16 + lq4 + r) * 72 + sp] = 0;
        } else {
            float dts = sdt[sp], cds = scd[sp];
            #pragma unroll
            for (int r = 0; r < 4; r++) {
                int tp = w * 16 + lq4 + r;
                float m = 0.f;
                if (sb < w || sp <= tp)
                    m = sacc[sb][r] * dts * __expf(Ah * (scd[tp] - cds));
                sM[tp * 72 + sp] = f2b(m);
            }
        }
    }

    // Y1 = M * X
    f32x4 yacc[4];
    #pragma unroll
    for (int pb = 0; pb < 4; pb++) yacc[pb] = (f32x4){0.f, 0.f, 0.f, 0.f};
    #pragma unroll
    for (int ks = 0; ks < 2; ks++) {
        if (ks == 1 && w < 2) continue;
        bf16x8 af = *(const bf16x8*)&sM[(w * 16 + lm) * 72 + ks * 32 + lq8];
        #pragma unroll
        for (int pb = 0; pb < 4; pb++) {
            bf16x8 bf_ = *(const bf16x8*)&sXT[(pb * 16 + lm) * 72 + ks * 32 + lq8];
            yacc[pb] = __builtin_amdgcn_mfma_f32_16x16x32_bf16(af, bf_, yacc[pb], 0, 0, 0);
        }
    }
    // Y2 = C * h_in^T
    f32x4 acc2[4];
    {
        bf16x8 cf2 = *(const bf16x8*)&sC[(w * 16 + lm) * 32 + lq8];
        #pragma unroll
        for (int pb = 0; pb < 4; pb++) {
            bf16x8 hf = *(const bf16x8*)&sHT[(pb * 16 + lm) * 40 + lq8];
            acc2[pb] = __builtin_amdgcn_mfma_f32_16x16x32_bf16(
                cf2, hf, (f32x4){0.f, 0.f, 0.f, 0.f}, 0, 0, 0);
        }
    }

    // ---- epilogue: gate with silu(z), single y write, ssq partials ----
    const float Dh = D_param[h];
    #pragma unroll
    for (int r = 0; r < 4; r++) {
        const int tp = w * 16 + lq4 + r;
        const size_t zrow = (size_t)(row0 + tp) * NPAD + h * 64;
        const size_t yrow = (size_t)(row0 + tp) * D_INNER + h * 64;
        float ssr = 0.f;
        #pragma unroll
        for (int pb = 0; pb < 4; pb++) {
            int pp = pb * 16 + lm;
            float xv = b2f(sXT[pp * 72 + tp]);
            float val = yacc[pb][r] + sSc[tp] * acc2[pb][r] + Dh * xv;
            float zv = b2f(zx[zrow + pp]);
            float yg = val * (zv / (1.f + __expf(-zv)));
            ssr += yg * yg;
            y[yrow + pp] = f2b(yg);
        }
        ssr += __shfl_xor(ssr, 1, 16);
        ssr += __shfl_xor(ssr, 2, 16);
        ssr += __shfl_xor(ssr, 4, 16);
        ssr += __shfl_xor(ssr, 8, 16);
        if (lm == 0)
            ssq[(size_t)(row0 + tp) * NHEADS + h] = ssr;
    }
}

// ---------- 5d. per-row rsqrt scale ----------
__global__ __launch_bounds__(256)
void rowscale_kernel(const float* __restrict__ ssq, float* __restrict__ rs) {
    int row = blockIdx.x * 256 + threadIdx.x;
    const float4* p = (const float4*)&ssq[(size_t)row * NHEADS];
    float s = 0.f;
    #pragma unroll
    for (int i = 0; i < 8; i++) {
        float4 v = p[i];
        s += v.x + v.y + v.z + v.w;
    }
    rs[row] = rsqrtf(s * (1.f / D_INNER) + 1e-5f);
}

// ---------- launcher ----------
extern "C" void kernel_launch(void* const* d_in, const int* in_sizes, int n_in,
                              void* d_out, int out_size, void* d_ws, size_t ws_size,
                              hipStream_t stream) {
    const float* x        = (const float*)d_in[0];
    const float* W_in     = (const float*)d_in[1];
    const float* conv_w   = (const float*)d_in[2];
    const float* conv_b   = (const float*)d_in[3];
    const float* dt_bias  = (const float*)d_in[4];
    const float* A_log    = (const float*)d_in[5];
    const float* D_param  = (const float*)d_in[6];
    const float* norm_w   = (const float*)d_in[7];
    const float* W_out    = (const float*)d_in[8];
    const float* ls       = (const float*)d_in[9];
    float* out = (float*)d_out;

    char* ws = (char*)d_ws;
    size_t off = 0;
    unsigned short* x_bf  = (unsigned short*)(ws + off); off += (size_t)MROWS * D_MODEL * 2;   // reused as hbuf
    unsigned short* winT  = (unsigned short*)(ws + off); off += (size_t)NPAD * D_MODEL * 2;
    unsigned short* woutT = (unsigned short*)(ws + off); off += (size_t)D_MODEL * D_INNER * 2;
    unsigned short* zx    = (unsigned short*)(ws + off); off += (size_t)MROWS * NPAD * 2;
    float*          pbuf  = (float*)(ws + off);          off += (size_t)BATCH * NHEADS * NCHUNK * 4;
    unsigned short* yb    = (unsigned short*)(ws + off); off += (size_t)MROWS * D_INNER * 2;
    float*          ssq   = (float*)(ws + off);          off += (size_t)MROWS * NHEADS * 4;
    float*          rsb   = (float*)(ws + off);          off += (size_t)MROWS * 4;
    float* hbuf = (float*)x_bf;   // x_bf dead after GEMM1; sizes match (16,777,216 B)

    cast_f32_bf16<<<(MROWS * D_MODEL) / 1024, 256, 0, stream>>>(x, x_bf, MROWS * D_MODEL);
    transpose_both<<<1568, 256, 0, stream>>>(W_in, winT, W_out, woutT, norm_w);
    gemm_bf16<0><<<(NPAD / 128) * 64, 256, 0, stream>>>(
        x_bf, winT, D_MODEL, NPAD, zx, nullptr, nullptr, nullptr, nullptr);
    ssd_hcomp<<<BATCH * NHEADS * NCHUNK, 256, 0, stream>>>(
        zx, dt_bias, conv_w, conv_b, A_log, hbuf, pbuf);
    ssd_state_scan<<<BATCH * NHEADS, 1024, 0, stream>>>(hbuf, pbuf);
    ssd_yfused<<<BATCH * NHEADS * NCHUNK, 256, 0, stream>>>(
        zx, dt_bias, conv_w, conv_b, A_log, D_param, hbuf, yb, ssq);
    rowscale_kernel<<<MROWS / 256, 256, 0, stream>>>(ssq, rsb);
    gemm_bf16<1><<<(D_MODEL / 128) * 64, 256, 0, stream>>>(
        yb, woutT, D_INNER, D_MODEL, nullptr, out, x, ls, rsb);
}

// Round 6
// 276.462 us; speedup vs baseline: 3.3056x; 1.2700x over previous
//
#include <hip/hip_runtime.h>
#include <hip/hip_bf16.h>

// ---------- constants ----------
#define D_MODEL   1024
#define D_STATE   16
#define D_CONV    4
#define HEADDIM   64
#define NHEADS    32
#define D_INNER   2048
#define CONV_DIM  2080           // D_INNER + 2*D_STATE
#define D_IN_PROJ 4160           // 2*D_INNER + 2*D_STATE + NHEADS
#define NPAD      4224           // D_IN_PROJ padded to x128
#define BATCH     4
#define SEQLEN    2048
#define MROWS     (BATCH*SEQLEN) // 8192
#define QCHUNK    64
#define NCHUNK    (SEQLEN/QCHUNK) // 32
#define DT_COL    (2*D_INNER + 2*D_STATE)   // 4128: dt raw column in zx

// weight pre-scale (better e4m3 utilization); inverses folded into epilogues
#define WSCALE    16.f
#define YSCALE    64.f

// ---------- helpers ----------
__device__ __forceinline__ unsigned short f2b(float f) {
    union { float f; unsigned int u; } v; v.f = f;
    unsigned int r = (v.u + 0x7FFFu + ((v.u >> 16) & 1u)) >> 16;
    return (unsigned short)r;
}
__device__ __forceinline__ float b2f(unsigned short h) {
    union { unsigned int u; float f; } v; v.u = ((unsigned int)h) << 16;
    return v.f;
}
__device__ __forceinline__ unsigned char f2fp8(float f) {
    return (unsigned char)(__builtin_amdgcn_cvt_pk_fp8_f32(f, 0.f, 0, false) & 0xFF);
}

typedef __attribute__((ext_vector_type(8))) short bf16x8;
typedef __attribute__((ext_vector_type(4))) float f32x4;
typedef __attribute__((ext_vector_type(4))) int   i32x4;
typedef __attribute__((ext_vector_type(8))) int   i32x8;

__device__ __forceinline__ i32x8 cat8(i32x4 a, i32x4 b) {
    i32x8 r;
    r[0] = a[0]; r[1] = a[1]; r[2] = a[2]; r[3] = a[3];
    r[4] = b[0]; r[5] = b[1]; r[6] = b[2]; r[7] = b[3];
    return r;
}

__device__ __forceinline__ void async_copy16b(const unsigned char* g, unsigned char* l) {
    __builtin_amdgcn_global_load_lds(
        (const __attribute__((address_space(1))) void*)g,
        (__attribute__((address_space(3))) void*)l, 16, 0, 0);
}

// ---------- 1. cast fp32 -> fp8 e4m3 ----------
__global__ void cast_f32_fp8(const float* __restrict__ in, unsigned char* __restrict__ out, int n) {
    int i = (blockIdx.x * blockDim.x + threadIdx.x) * 4;
    if (i >= n) return;
    float4 v = *(const float4*)&in[i];
    int p = __builtin_amdgcn_cvt_pk_fp8_f32(v.x, v.y, 0, false);
    p = __builtin_amdgcn_cvt_pk_fp8_f32(v.z, v.w, p, true);
    *(unsigned int*)&out[i] = (unsigned int)p;
}

// ---------- 2. both weight transposes -> fp8 (x WSCALE, W_out also x norm_w) ----------
__global__ void transpose_both(const float* __restrict__ W_in, unsigned char* __restrict__ winT,
                               const float* __restrict__ W_out, unsigned char* __restrict__ woutT,
                               const float* __restrict__ norm_w) {
    __shared__ float tile[64][65];
    int bid = blockIdx.x;
    const float* W; unsigned char* WT; const float* kscale;
    int K, N, bx, by;
    if (bid < 1056) { W = W_in;  WT = winT;  kscale = nullptr; K = 1024; N = 4160; bx = bid % 66; by = bid / 66; }
    else { bid -= 1056; W = W_out; WT = woutT; kscale = norm_w; K = 2048; N = 1024; bx = bid % 16; by = bid / 16; }
    int n0 = bx * 64, k0 = by * 64;
    int tx = threadIdx.x & 63, ty = threadIdx.x >> 6;
    #pragma unroll
    for (int i = 0; i < 16; i++) {
        int r = ty * 16 + i;
        int n = n0 + tx;
        float v = (n < N) ? W[(size_t)(k0 + r) * N + n] : 0.f;
        tile[r][tx] = v;
    }
    __syncthreads();
    float ks = WSCALE * (kscale ? kscale[k0 + tx] : 1.f);
    #pragma unroll
    for (int i = 0; i < 16; i++) {
        int r = ty * 16 + i;
        WT[(size_t)(n0 + r) * K + k0 + tx] = f2fp8(tile[tx][r] * ks);
    }
}

// ---------- 3. fp8 MFMA GEMM (MX-scaled K=128, unit scales), BK=128, XOR swizzle, XCD remap ----------
// A[M][K] fp8, B[N][K] fp8.  EPI 0: zx bf16 = v/WSCALE.  EPI 1: out = xres + v*ls*rs/(WSCALE*YSCALE).
template <int EPI>
__global__ __launch_bounds__(256)
void gemm_fp8(const unsigned char* __restrict__ A, const unsigned char* __restrict__ B,
              int K, int N, unsigned short* __restrict__ Cb,
              float* __restrict__ Cf, const float* __restrict__ xres,
              const float* __restrict__ ls, const float* __restrict__ rs) {
    __shared__ unsigned char lds_a[128 * 128];
    __shared__ unsigned char lds_b[128 * 128];
    const int tid  = threadIdx.x;
    const int wave = tid >> 6;
    const int lane = tid & 63;
    const int bid = blockIdx.x;
    const int xcd = bid & 7, g = bid >> 3;
    const int bm = xcd * 8 + (g & 7);
    const int bn = g >> 3;
    const int wm = wave >> 1, wn = wave & 1;

    f32x4 acc[4][4];
    #pragma unroll
    for (int i = 0; i < 4; i++)
        #pragma unroll
        for (int j = 0; j < 4; j++) acc[i][j] = (f32x4){0.f, 0.f, 0.f, 0.f};

    // staging: rows of 128 B = 8 segs x 16 B; lane L -> phys seg L&7 of row base+(L>>3);
    // source logical seg = (L&7)^((L>>3)&7)  => phys seg p of row r holds logical seg p^(r&7)
    const int srow = lane >> 3;
    const int sseg = (lane & 7) ^ srow;
    const unsigned char* gA0 = A + (size_t)(bm * 128 + wave * 8 + srow) * K + sseg * 16;
    const unsigned char* gB0 = B + (size_t)(bn * 128 + wave * 8 + srow) * K + sseg * 16;
    const int ldsbase = wave * 8 * 128;

    const int lm = lane & 15, q = lane >> 4;

    for (int k0 = 0; k0 < K; k0 += 128) {
        #pragma unroll
        for (int j = 0; j < 4; j++) {
            async_copy16b(gA0 + k0 + (size_t)(j * 32) * K, &lds_a[ldsbase + j * 32 * 128]);
            async_copy16b(gB0 + k0 + (size_t)(j * 32) * K, &lds_b[ldsbase + j * 32 * 128]);
        }
        __syncthreads();

        i32x8 af[4], bfr[4];
        #pragma unroll
        for (int i = 0; i < 4; i++) {
            int r = wm * 64 + i * 16 + lm;
            int s0 = ((2 * q) ^ (r & 7)) * 16, s1 = ((2 * q + 1) ^ (r & 7)) * 16;
            af[i] = cat8(*(const i32x4*)&lds_a[r * 128 + s0],
                         *(const i32x4*)&lds_a[r * 128 + s1]);
        }
        #pragma unroll
        for (int j = 0; j < 4; j++) {
            int r = wn * 64 + j * 16 + lm;
            int s0 = ((2 * q) ^ (r & 7)) * 16, s1 = ((2 * q + 1) ^ (r & 7)) * 16;
            bfr[j] = cat8(*(const i32x4*)&lds_b[r * 128 + s0],
                          *(const i32x4*)&lds_b[r * 128 + s1]);
        }
        #pragma unroll
        for (int i = 0; i < 4; i++)
            #pragma unroll
            for (int j = 0; j < 4; j++)
                acc[i][j] = __builtin_amdgcn_mfma_scale_f32_16x16x128_f8f6f4(
                    af[i], bfr[j], acc[i][j], 0, 0,
                    0, 0x7F7F7F7F, 0, 0x7F7F7F7F);   // e4m3/e4m3, unit e8m0 scales
        __syncthreads();
    }

    const int row0 = bm * 128 + wm * 64;
    const int col0 = bn * 128 + wn * 64;
    const int lq = (lane >> 4) * 4;
    #pragma unroll
    for (int i = 0; i < 4; i++) {
        #pragma unroll
        for (int j = 0; j < 4; j++) {
            #pragma unroll
            for (int r = 0; r < 4; r++) {
                int gr = row0 + i * 16 + lq + r;
                int gc = col0 + j * 16 + lm;
                float v = acc[i][j][r];
                if (EPI == 0) {
                    Cb[(size_t)gr * N + gc] = f2b(v * (1.f / WSCALE));
                } else {
                    size_t idx = (size_t)gr * 1024 + gc;
                    Cf[idx] = xres[idx] + v * ls[gc] * rs[gr] * (1.f / (WSCALE * YSCALE));
                }
            }
        }
    }
}

// ---------- 5a. chunk-local state (conv fused): h_local = (B.w)^T X ----------
__global__ __launch_bounds__(256)
void ssd_hcomp(const unsigned short* __restrict__ zx, const float* __restrict__ dt_bias,
               const float* __restrict__ conv_w, const float* __restrict__ conv_b,
               const float* __restrict__ A_log,
               float* __restrict__ hbuf, float* __restrict__ pbuf) {
    __shared__ unsigned short sXraw[67 * 64];
    __shared__ unsigned short sBraw[67 * 32];
    __shared__ unsigned short sXT[64 * 72];
    __shared__ unsigned short sBwT[16 * 72];
    __shared__ float sdt[64], scd[64];

    const int blk = blockIdx.x;
    const int c  = blk & 31;
    const int h  = (blk >> 5) & 31;
    const int b  = blk >> 10;
    const int bh = blk >> 5;
    const int row0 = b * SEQLEN + c * QCHUNK;
    const int batch0 = b * SEQLEN;

    const int t    = threadIdx.x;
    const int w    = t >> 6;
    const int lane = t & 63;
    const int lm   = lane & 15;
    const int lq8  = (lane >> 4) * 8;
    const int lq4  = (lane >> 4) * 4;
    const float Ah = -__expf(A_log[h]);

    for (int i = t; i < 536; i += 256) {
        int r = i >> 3, seg = i & 7;
        int gr = row0 - 3 + r;
        int4 v = (gr >= batch0) ? *(const int4*)&zx[(size_t)gr * NPAD + D_INNER + h * 64 + seg * 8]
                                : (int4){0, 0, 0, 0};
        *(int4*)&sXraw[r * 64 + seg * 8] = v;
    }
    for (int i = t; i < 268; i += 256) {
        int r = i >> 2, seg = i & 3;
        int gr = row0 - 3 + r;
        int4 v = (gr >= batch0) ? *(const int4*)&zx[(size_t)gr * NPAD + 2 * D_INNER + seg * 8]
                                : (int4){0, 0, 0, 0};
        *(int4*)&sBraw[r * 32 + seg * 8] = v;
    }
    if (t < 64) {
        float raw = b2f(zx[(size_t)(row0 + t) * NPAD + DT_COL + h]) + dt_bias[h];
        float dtv = (raw > 20.f) ? raw : log1pf(__expf(raw));
        float v = dtv;
        #pragma unroll
        for (int o = 1; o < 64; o <<= 1) {
            float u = __shfl_up(v, o, 64);
            if (t >= o) v += u;
        }
        sdt[t] = dtv;
        scd[t] = v;
        if (t == 63) pbuf[bh * NCHUNK + c] = __expf(Ah * v);
    }
    __syncthreads();

    {   // conv+silu X
        const int p = t & 63, sblk = (t >> 6) * 16;
        const int ch = h * 64 + p;
        const float cw0 = conv_w[ch * 4 + 0], cw1 = conv_w[ch * 4 + 1];
        const float cw2 = conv_w[ch * 4 + 2], cw3 = conv_w[ch * 4 + 3];
        const float cb = conv_b[ch];
        #pragma unroll
        for (int i = 0; i < 16; i++) {
            int s = sblk + i;
            float acc = cb + cw0 * b2f(sXraw[s * 64 + p]) + cw1 * b2f(sXraw[(s + 1) * 64 + p])
                           + cw2 * b2f(sXraw[(s + 2) * 64 + p]) + cw3 * b2f(sXraw[(s + 3) * 64 + p]);
            float sv = acc / (1.f + __expf(-acc));
            sXT[p * 72 + s] = f2b(sv);
        }
    }
    {   // conv+silu B with dt*decay weight
        const int n = t & 15, s0 = (t >> 4) * 4;
        const int ch = D_INNER + n;
        const float cw0 = conv_w[ch * 4 + 0], cw1 = conv_w[ch * 4 + 1];
        const float cw2 = conv_w[ch * 4 + 2], cw3 = conv_w[ch * 4 + 3];
        const float cb = conv_b[ch];
        const float cdl = scd[63];
        #pragma unroll
        for (int i = 0; i < 4; i++) {
            int s = s0 + i;
            float acc = cb + cw0 * b2f(sBraw[s * 32 + n]) + cw1 * b2f(sBraw[(s + 1) * 32 + n])
                           + cw2 * b2f(sBraw[(s + 2) * 32 + n]) + cw3 * b2f(sBraw[(s + 3) * 32 + n]);
            float sv = acc / (1.f + __expf(-acc));
            float wgt = sdt[s] * __expf(Ah * (cdl - scd[s]));
            sBwT[n * 72 + s] = f2b(sv * wgt);
        }
    }
    __syncthreads();

    f32x4 hacc = (f32x4){0.f, 0.f, 0.f, 0.f};
    #pragma unroll
    for (int ks = 0; ks < 2; ks++) {
        bf16x8 af = *(const bf16x8*)&sBwT[lm * 72 + ks * 32 + lq8];
        bf16x8 bf_ = *(const bf16x8*)&sXT[(w * 16 + lm) * 72 + ks * 32 + lq8];
        hacc = __builtin_amdgcn_mfma_f32_16x16x32_bf16(af, bf_, hacc, 0, 0, 0);
    }
    #pragma unroll
    for (int r = 0; r < 4; r++)
        hbuf[(size_t)(bh * NCHUNK + c) * 1024 + (lq4 + r) * 64 + (w * 16 + lm)] = hacc[r];
}

// ---------- 5b. inter-chunk state scan: register-prefetched ----------
__global__ __launch_bounds__(1024)
void ssd_state_scan(float* __restrict__ hbuf, const float* __restrict__ pbuf) {
    int bh = blockIdx.x;
    int t = threadIdx.x;
    __shared__ float sP[NCHUNK];
    if (t < NCHUNK) sP[t] = pbuf[bh * NCHUNK + t];
    __syncthreads();
    size_t base = (size_t)bh * NCHUNK * 1024 + t;
    float v[NCHUNK];
    #pragma unroll
    for (int c = 0; c < NCHUNK; c++) v[c] = hbuf[base + (size_t)c * 1024];
    float carry = 0.f;
    #pragma unroll
    for (int c = 0; c < NCHUNK; c++) {
        float tmp = v[c];
        v[c] = carry;
        carry = tmp + sP[c] * carry;
    }
    #pragma unroll
    for (int c = 0; c < NCHUNK; c++) hbuf[base + (size_t)c * 1024] = v[c];
}

// ---------- 5c. fused y (conv fused): yq = fp8(YSCALE * (M.X + D*x + scale*(C.h_in)) * silu(z)) ----------
__global__ __launch_bounds__(256)
void ssd_yfused(const unsigned short* __restrict__ zx, const float* __restrict__ dt_bias,
                const float* __restrict__ conv_w, const float* __restrict__ conv_b,
                const float* __restrict__ A_log, const float* __restrict__ D_param,
                const float* __restrict__ hbuf,
                unsigned char* __restrict__ y, float* __restrict__ ssq) {
    __shared__ unsigned short sXraw[67 * 64];
    __shared__ unsigned short sBCraw[67 * 32];
    __shared__ unsigned short sB[64 * 32];
    __shared__ unsigned short sC[64 * 32];
    __shared__ unsigned short sXT[64 * 72];
    __shared__ unsigned short sM[64 * 72];
    __shared__ unsigned short sHT[64 * 40];
    __shared__ float sdt[64], scd[64], sSc[64];

    const int blk = blockIdx.x;
    const int c  = blk & 31;
    const int h  = (blk >> 5) & 31;
    const int b  = blk >> 10;
    const int bh = blk >> 5;
    const int row0 = b * SEQLEN + c * QCHUNK;
    const int batch0 = b * SEQLEN;

    const int t    = threadIdx.x;
    const int w    = t >> 6;
    const int lane = t & 63;
    const int lm   = lane & 15;
    const int lq8  = (lane >> 4) * 8;
    const int lq4  = (lane >> 4) * 4;
    const float Ah = -__expf(A_log[h]);

    for (int i = t; i < 536; i += 256) {
        int r = i >> 3, seg = i & 7;
        int gr = row0 - 3 + r;
        int4 v = (gr >= batch0) ? *(const int4*)&zx[(size_t)gr * NPAD + D_INNER + h * 64 + seg * 8]
                                : (int4){0, 0, 0, 0};
        *(int4*)&sXraw[r * 64 + seg * 8] = v;
    }
    for (int i = t; i < 268; i += 256) {
        int r = i >> 2, seg = i & 3;
        int gr = row0 - 3 + r;
        int4 v = (gr >= batch0) ? *(const int4*)&zx[(size_t)gr * NPAD + 2 * D_INNER + seg * 8]
                                : (int4){0, 0, 0, 0};
        *(int4*)&sBCraw[r * 32 + seg * 8] = v;
    }
    {   // h_in -> sHT [p][n] bf16
        size_t hb = (size_t)(bh * NCHUNK + c) * 1024 + (size_t)t * 4;
        float4 hv = *(const float4*)&hbuf[hb];
        int n = t >> 4;
        int p0 = (t * 4) & 63;
        sHT[(p0 + 0) * 40 + n] = f2b(hv.x);
        sHT[(p0 + 1) * 40 + n] = f2b(hv.y);
        sHT[(p0 + 2) * 40 + n] = f2b(hv.z);
        sHT[(p0 + 3) * 40 + n] = f2b(hv.w);
    }
    if (t < 64) {
        float raw = b2f(zx[(size_t)(row0 + t) * NPAD + DT_COL + h]) + dt_bias[h];
        float dtv = (raw > 20.f) ? raw : log1pf(__expf(raw));
        float v = dtv;
        #pragma unroll
        for (int o = 1; o < 64; o <<= 1) {
            float u = __shfl_up(v, o, 64);
            if (t >= o) v += u;
        }
        sdt[t] = dtv;
        scd[t] = v;
        sSc[t] = __expf(Ah * v);
    } else if (t < 128) {
        int tt = t - 64;
        *(int4*)&sHT[tt * 40 + 16] = (int4){0, 0, 0, 0};
        *(int4*)&sHT[tt * 40 + 24] = (int4){0, 0, 0, 0};
    }
    __syncthreads();

    {   // conv+silu X
        const int p = t & 63, sblk = (t >> 6) * 16;
        const int ch = h * 64 + p;
        const float cw0 = conv_w[ch * 4 + 0], cw1 = conv_w[ch * 4 + 1];
        const float cw2 = conv_w[ch * 4 + 2], cw3 = conv_w[ch * 4 + 3];
        const float cb = conv_b[ch];
        #pragma unroll
        for (int i = 0; i < 16; i++) {
            int s = sblk + i;
            float acc = cb + cw0 * b2f(sXraw[s * 64 + p]) + cw1 * b2f(sXraw[(s + 1) * 64 + p])
                           + cw2 * b2f(sXraw[(s + 2) * 64 + p]) + cw3 * b2f(sXraw[(s + 3) * 64 + p]);
            float sv = acc / (1.f + __expf(-acc));
            sXT[p * 72 + s] = f2b(sv);
        }
    }
    {   // conv+silu B and C
        const int ch32 = t & 31, s0 = (t >> 5) * 8;
        const int ch = D_INNER + ch32;
        const float cw0 = conv_w[ch * 4 + 0], cw1 = conv_w[ch * 4 + 1];
        const float cw2 = conv_w[ch * 4 + 2], cw3 = conv_w[ch * 4 + 3];
        const float cb = conv_b[ch];
        unsigned short* dst = (ch32 < 16) ? &sB[ch32] : &sC[ch32 - 16];
        #pragma unroll
        for (int i = 0; i < 8; i++) {
            int s = s0 + i;
            float acc = cb + cw0 * b2f(sBCraw[s * 32 + ch32]) + cw1 * b2f(sBCraw[(s + 1) * 32 + ch32])
                           + cw2 * b2f(sBCraw[(s + 2) * 32 + ch32]) + cw3 * b2f(sBCraw[(s + 3) * 32 + ch32]);
            float sv = acc / (1.f + __expf(-acc));
            dst[s * 32] = f2b(sv);
        }
    }
    if (t < 64) {
        *(int4*)&sB[t * 32 + 16] = (int4){0, 0, 0, 0};
        *(int4*)&sB[t * 32 + 24] = (int4){0, 0, 0, 0};
        *(int4*)&sC[t * 32 + 16] = (int4){0, 0, 0, 0};
        *(int4*)&sC[t * 32 + 24] = (int4){0, 0, 0, 0};
    }
    __syncthreads();

    f32x4 sacc[4];
    {
        bf16x8 cfrag = *(const bf16x8*)&sC[(w * 16 + lm) * 32 + lq8];
        #pragma unroll
        for (int sb = 0; sb < 4; sb++) {
            if (sb <= w) {
                bf16x8 bfrag = *(const bf16x8*)&sB[(sb * 16 + lm) * 32 + lq8];
                sacc[sb] = __builtin_amdgcn_mfma_f32_16x16x32_bf16(
                    cfrag, bfrag, (f32x4){0.f, 0.f, 0.f, 0.f}, 0, 0, 0);
            }
        }
    }
    #pragma unroll
    for (int sb = 0; sb < 4; sb++) {
        int sp = sb * 16 + lm;
        if (sb > w) {
            #pragma unroll
            for (int r = 0; r < 4; r++) sM[(w * 16 + lq4 + r) * 72 + sp] = 0;
        } else {
            float dts = sdt[sp], cds = scd[sp];
            #pragma unroll
            for (int r = 0; r < 4; r++) {
                int tp = w * 16 + lq4 + r;
                float m = 0.f;
                if (sb < w || sp <= tp)
                    m = sacc[sb][r] * dts * __expf(Ah * (scd[tp] - cds));
                sM[tp * 72 + sp] = f2b(m);
            }
        }
    }

    f32x4 yacc[4];
    #pragma unroll
    for (int pb = 0; pb < 4; pb++) yacc[pb] = (f32x4){0.f, 0.f, 0.f, 0.f};
    #pragma unroll
    for (int ks = 0; ks < 2; ks++) {
        if (ks == 1 && w < 2) continue;
        bf16x8 af = *(const bf16x8*)&sM[(w * 16 + lm) * 72 + ks * 32 + lq8];
        #pragma unroll
        for (int pb = 0; pb < 4; pb++) {
            bf16x8 bf_ = *(const bf16x8*)&sXT[(pb * 16 + lm) * 72 + ks * 32 + lq8];
            yacc[pb] = __builtin_amdgcn_mfma_f32_16x16x32_bf16(af, bf_, yacc[pb], 0, 0, 0);
        }
    }
    f32x4 acc2[4];
    {
        bf16x8 cf2 = *(const bf16x8*)&sC[(w * 16 + lm) * 32 + lq8];
        #pragma unroll
        for (int pb = 0; pb < 4; pb++) {
            bf16x8 hf = *(const bf16x8*)&sHT[(pb * 16 + lm) * 40 + lq8];
            acc2[pb] = __builtin_amdgcn_mfma_f32_16x16x32_bf16(
                cf2, hf, (f32x4){0.f, 0.f, 0.f, 0.f}, 0, 0, 0);
        }
    }

    const float Dh = D_param[h];
    #pragma unroll
    for (int r = 0; r < 4; r++) {
        const int tp = w * 16 + lq4 + r;
        const size_t zrow = (size_t)(row0 + tp) * NPAD + h * 64;
        const size_t yrow = (size_t)(row0 + tp) * D_INNER + h * 64;
        float ssr = 0.f;
        #pragma unroll
        for (int pb = 0; pb < 4; pb++) {
            int pp = pb * 16 + lm;
            float xv = b2f(sXT[pp * 72 + tp]);
            float val = yacc[pb][r] + sSc[tp] * acc2[pb][r] + Dh * xv;
            float zv = b2f(zx[zrow + pp]);
            float yg = val * (zv / (1.f + __expf(-zv)));
            ssr += yg * yg;
            y[yrow + pp] = f2fp8(yg * YSCALE);
        }
        ssr += __shfl_xor(ssr, 1, 16);
        ssr += __shfl_xor(ssr, 2, 16);
        ssr += __shfl_xor(ssr, 4, 16);
        ssr += __shfl_xor(ssr, 8, 16);
        if (lm == 0)
            ssq[(size_t)(row0 + tp) * NHEADS + h] = ssr;
    }
}

// ---------- 5d. per-row rsqrt scale ----------
__global__ __launch_bounds__(256)
void rowscale_kernel(const float* __restrict__ ssq, float* __restrict__ rs) {
    int row = blockIdx.x * 256 + threadIdx.x;
    const float4* p = (const float4*)&ssq[(size_t)row * NHEADS];
    float s = 0.f;
    #pragma unroll
    for (int i = 0; i < 8; i++) {
        float4 v = p[i];
        s += v.x + v.y + v.z + v.w;
    }
    rs[row] = rsqrtf(s * (1.f / D_INNER) + 1e-5f);
}

// ---------- launcher ----------
extern "C" void kernel_launch(void* const* d_in, const int* in_sizes, int n_in,
                              void* d_out, int out_size, void* d_ws, size_t ws_size,
                              hipStream_t stream) {
    const float* x        = (const float*)d_in[0];
    const float* W_in     = (const float*)d_in[1];
    const float* conv_w   = (const float*)d_in[2];
    const float* conv_b   = (const float*)d_in[3];
    const float* dt_bias  = (const float*)d_in[4];
    const float* A_log    = (const float*)d_in[5];
    const float* D_param  = (const float*)d_in[6];
    const float* norm_w   = (const float*)d_in[7];
    const float* W_out    = (const float*)d_in[8];
    const float* ls       = (const float*)d_in[9];
    float* out = (float*)d_out;

    char* ws = (char*)d_ws;
    size_t off = 0;
    unsigned char*  x_f8  = (unsigned char*)(ws + off);  off += (size_t)MROWS * D_MODEL;       // 8.4 MB
    unsigned char*  winT  = (unsigned char*)(ws + off);  off += (size_t)NPAD * D_MODEL;        // 4.3 MB
    unsigned char*  woutT = (unsigned char*)(ws + off);  off += (size_t)D_MODEL * D_INNER;     // 2.1 MB
    unsigned short* zx    = (unsigned short*)(ws + off); off += (size_t)MROWS * NPAD * 2;      // 69.2 MB
    float*          pbuf  = (float*)(ws + off);          off += (size_t)BATCH * NHEADS * NCHUNK * 4;
    unsigned char*  yb    = (unsigned char*)(ws + off);  off += (size_t)MROWS * D_INNER;       // 16.8 MB
    float*          ssq   = (float*)(ws + off);          off += (size_t)MROWS * NHEADS * 4;    // 1 MB
    float*          rsb   = (float*)(ws + off);          off += (size_t)MROWS * 4;
    float*          hbuf  = (float*)(ws + off);          off += (size_t)BATCH * NHEADS * NCHUNK * 1024 * 4; // 16.8 MB

    cast_f32_fp8<<<(MROWS * D_MODEL) / 1024, 256, 0, stream>>>(x, x_f8, MROWS * D_MODEL);
    transpose_both<<<1568, 256, 0, stream>>>(W_in, winT, W_out, woutT, norm_w);
    gemm_fp8<0><<<(NPAD / 128) * 64, 256, 0, stream>>>(
        x_f8, winT, D_MODEL, NPAD, zx, nullptr, nullptr, nullptr, nullptr);
    ssd_hcomp<<<BATCH * NHEADS * NCHUNK, 256, 0, stream>>>(
        zx, dt_bias, conv_w, conv_b, A_log, hbuf, pbuf);
    ssd_state_scan<<<BATCH * NHEADS, 1024, 0, stream>>>(hbuf, pbuf);
    ssd_yfused<<<BATCH * NHEADS * NCHUNK, 256, 0, stream>>>(
        zx, dt_bias, conv_w, conv_b, A_log, D_param, hbuf, yb, ssq);
    rowscale_kernel<<<MROWS / 256, 256, 0, stream>>>(ssq, rsb);
    gemm_fp8<1><<<(D_MODEL / 128) * 64, 256, 0, stream>>>(
        yb, woutT, D_INNER, D_MODEL, nullptr, out, x, ls, rsb);
}

// Round 7
// 268.967 us; speedup vs baseline: 3.3977x; 1.0279x over previous
//
#include <hip/hip_runtime.h>
#include <hip/hip_bf16.h>

// ---------- constants ----------
#define D_MODEL   1024
#define D_STATE   16
#define D_CONV    4
#define HEADDIM   64
#define NHEADS    32
#define D_INNER   2048
#define CONV_DIM  2080           // D_INNER + 2*D_STATE
#define D_IN_PROJ 4160           // 2*D_INNER + 2*D_STATE + NHEADS
#define NPAD      4224           // D_IN_PROJ padded to x128
#define BATCH     4
#define SEQLEN    2048
#define MROWS     (BATCH*SEQLEN) // 8192
#define QCHUNK    64
#define NCHUNK    (SEQLEN/QCHUNK) // 32
#define DT_COL    (2*D_INNER + 2*D_STATE)   // 4128: dt raw column in zx

// weight pre-scale (better e4m3 utilization); inverses folded into epilogues
#define WSCALE    16.f
#define YSCALE    64.f

// ---------- helpers ----------
__device__ __forceinline__ unsigned short f2b(float f) {
    union { float f; unsigned int u; } v; v.f = f;
    unsigned int r = (v.u + 0x7FFFu + ((v.u >> 16) & 1u)) >> 16;
    return (unsigned short)r;
}
__device__ __forceinline__ float b2f(unsigned short h) {
    union { unsigned int u; float f; } v; v.u = ((unsigned int)h) << 16;
    return v.f;
}
__device__ __forceinline__ unsigned char f2fp8(float f) {
    return (unsigned char)(__builtin_amdgcn_cvt_pk_fp8_f32(f, 0.f, 0, false) & 0xFF);
}

typedef __attribute__((ext_vector_type(8))) short bf16x8;
typedef __attribute__((ext_vector_type(4))) float f32x4;
typedef __attribute__((ext_vector_type(4))) int   i32x4;
typedef __attribute__((ext_vector_type(8))) int   i32x8;

__device__ __forceinline__ i32x8 cat8(i32x4 a, i32x4 b) {
    i32x8 r;
    r[0] = a[0]; r[1] = a[1]; r[2] = a[2]; r[3] = a[3];
    r[4] = b[0]; r[5] = b[1]; r[6] = b[2]; r[7] = b[3];
    return r;
}

__device__ __forceinline__ void async_copy16b(const unsigned char* g, unsigned char* l) {
    __builtin_amdgcn_global_load_lds(
        (const __attribute__((address_space(1))) void*)g,
        (__attribute__((address_space(3))) void*)l, 16, 0, 0);
}

// ---------- 1. cast fp32 -> fp8 e4m3 ----------
__global__ void cast_f32_fp8(const float* __restrict__ in, unsigned char* __restrict__ out, int n) {
    int i = (blockIdx.x * blockDim.x + threadIdx.x) * 4;
    if (i >= n) return;
    float4 v = *(const float4*)&in[i];
    int p = __builtin_amdgcn_cvt_pk_fp8_f32(v.x, v.y, 0, false);
    p = __builtin_amdgcn_cvt_pk_fp8_f32(v.z, v.w, p, true);
    *(unsigned int*)&out[i] = (unsigned int)p;
}

// ---------- 2. both weight transposes -> fp8 (x WSCALE, W_out also x norm_w) ----------
__global__ void transpose_both(const float* __restrict__ W_in, unsigned char* __restrict__ winT,
                               const float* __restrict__ W_out, unsigned char* __restrict__ woutT,
                               const float* __restrict__ norm_w) {
    __shared__ float tile[64][65];
    int bid = blockIdx.x;
    const float* W; unsigned char* WT; const float* kscale;
    int K, N, bx, by;
    if (bid < 1056) { W = W_in;  WT = winT;  kscale = nullptr; K = 1024; N = 4160; bx = bid % 66; by = bid / 66; }
    else { bid -= 1056; W = W_out; WT = woutT; kscale = norm_w; K = 2048; N = 1024; bx = bid % 16; by = bid / 16; }
    int n0 = bx * 64, k0 = by * 64;
    int tx = threadIdx.x & 63, ty = threadIdx.x >> 6;
    #pragma unroll
    for (int i = 0; i < 16; i++) {
        int r = ty * 16 + i;
        int n = n0 + tx;
        float v = (n < N) ? W[(size_t)(k0 + r) * N + n] : 0.f;
        tile[r][tx] = v;
    }
    __syncthreads();
    float ks = WSCALE * (kscale ? kscale[k0 + tx] : 1.f);
    #pragma unroll
    for (int i = 0; i < 16; i++) {
        int r = ty * 16 + i;
        WT[(size_t)(n0 + r) * K + k0 + tx] = f2fp8(tile[tx][r] * ks);
    }
}

// ---------- 3. fp8 MFMA GEMM (MX-scaled K=128, unit scales), BK=128, XOR swizzle, XCD remap ----------
template <int EPI>
__global__ __launch_bounds__(256)
void gemm_fp8(const unsigned char* __restrict__ A, const unsigned char* __restrict__ B,
              int K, int N, unsigned short* __restrict__ Cb,
              float* __restrict__ Cf, const float* __restrict__ xres,
              const float* __restrict__ ls, const float* __restrict__ rs) {
    __shared__ unsigned char lds_a[128 * 128];
    __shared__ unsigned char lds_b[128 * 128];
    const int tid  = threadIdx.x;
    const int wave = tid >> 6;
    const int lane = tid & 63;
    const int bid = blockIdx.x;
    const int xcd = bid & 7, g = bid >> 3;
    const int bm = xcd * 8 + (g & 7);
    const int bn = g >> 3;
    const int wm = wave >> 1, wn = wave & 1;

    f32x4 acc[4][4];
    #pragma unroll
    for (int i = 0; i < 4; i++)
        #pragma unroll
        for (int j = 0; j < 4; j++) acc[i][j] = (f32x4){0.f, 0.f, 0.f, 0.f};

    const int srow = lane >> 3;
    const int sseg = (lane & 7) ^ srow;
    const unsigned char* gA0 = A + (size_t)(bm * 128 + wave * 8 + srow) * K + sseg * 16;
    const unsigned char* gB0 = B + (size_t)(bn * 128 + wave * 8 + srow) * K + sseg * 16;
    const int ldsbase = wave * 8 * 128;

    const int lm = lane & 15, q = lane >> 4;

    for (int k0 = 0; k0 < K; k0 += 128) {
        #pragma unroll
        for (int j = 0; j < 4; j++) {
            async_copy16b(gA0 + k0 + (size_t)(j * 32) * K, &lds_a[ldsbase + j * 32 * 128]);
            async_copy16b(gB0 + k0 + (size_t)(j * 32) * K, &lds_b[ldsbase + j * 32 * 128]);
        }
        __syncthreads();

        i32x8 af[4], bfr[4];
        #pragma unroll
        for (int i = 0; i < 4; i++) {
            int r = wm * 64 + i * 16 + lm;
            int s0 = ((2 * q) ^ (r & 7)) * 16, s1 = ((2 * q + 1) ^ (r & 7)) * 16;
            af[i] = cat8(*(const i32x4*)&lds_a[r * 128 + s0],
                         *(const i32x4*)&lds_a[r * 128 + s1]);
        }
        #pragma unroll
        for (int j = 0; j < 4; j++) {
            int r = wn * 64 + j * 16 + lm;
            int s0 = ((2 * q) ^ (r & 7)) * 16, s1 = ((2 * q + 1) ^ (r & 7)) * 16;
            bfr[j] = cat8(*(const i32x4*)&lds_b[r * 128 + s0],
                          *(const i32x4*)&lds_b[r * 128 + s1]);
        }
        #pragma unroll
        for (int i = 0; i < 4; i++)
            #pragma unroll
            for (int j = 0; j < 4; j++)
                acc[i][j] = __builtin_amdgcn_mfma_scale_f32_16x16x128_f8f6f4(
                    af[i], bfr[j], acc[i][j], 0, 0,
                    0, 0x7F7F7F7F, 0, 0x7F7F7F7F);
        __syncthreads();
    }

    const int row0 = bm * 128 + wm * 64;
    const int col0 = bn * 128 + wn * 64;
    const int lq = (lane >> 4) * 4;
    #pragma unroll
    for (int i = 0; i < 4; i++) {
        #pragma unroll
        for (int j = 0; j < 4; j++) {
            #pragma unroll
            for (int r = 0; r < 4; r++) {
                int gr = row0 + i * 16 + lq + r;
                int gc = col0 + j * 16 + lm;
                float v = acc[i][j][r];
                if (EPI == 0) {
                    Cb[(size_t)gr * N + gc] = f2b(v * (1.f / WSCALE));
                } else {
                    size_t idx = (size_t)gr * 1024 + gc;
                    Cf[idx] = xres[idx] + v * ls[gc] * rs[gr] * (1.f / (WSCALE * YSCALE));
                }
            }
        }
    }
}

// ---------- 5a. conv + chunk-local state; persists conv(X)^T, conv(B/C), dt/cd/scale ----------
__global__ __launch_bounds__(256)
void ssd_hcomp(const unsigned short* __restrict__ zx, const float* __restrict__ dt_bias,
               const float* __restrict__ conv_w, const float* __restrict__ conv_b,
               const float* __restrict__ A_log,
               float* __restrict__ hbuf, float* __restrict__ pbuf,
               unsigned short* __restrict__ xTg, unsigned short* __restrict__ bcg,
               float* __restrict__ scA) {
    __shared__ unsigned short sXraw[67 * 64];
    __shared__ unsigned short sBCraw[67 * 32];
    __shared__ unsigned short sXT[64 * 72];
    __shared__ unsigned short sBC[64 * 32];
    __shared__ unsigned short sBwT[16 * 72];
    __shared__ float sdt[64], scd[64];

    const int blk = blockIdx.x;
    const int c  = blk & 31;
    const int h  = (blk >> 5) & 31;
    const int b  = blk >> 10;
    const int bh = blk >> 5;
    const int row0 = b * SEQLEN + c * QCHUNK;
    const int batch0 = b * SEQLEN;

    const int t    = threadIdx.x;
    const int w    = t >> 6;
    const int lane = t & 63;
    const int lm   = lane & 15;
    const int lq8  = (lane >> 4) * 8;
    const int lq4  = (lane >> 4) * 4;
    const float Ah = -__expf(A_log[h]);

    // ---- phase 1: halo staging + dt softplus/prefix ----
    for (int i = t; i < 536; i += 256) {
        int r = i >> 3, seg = i & 7;
        int gr = row0 - 3 + r;
        int4 v = (gr >= batch0) ? *(const int4*)&zx[(size_t)gr * NPAD + D_INNER + h * 64 + seg * 8]
                                : (int4){0, 0, 0, 0};
        *(int4*)&sXraw[r * 64 + seg * 8] = v;
    }
    for (int i = t; i < 268; i += 256) {
        int r = i >> 2, seg = i & 3;
        int gr = row0 - 3 + r;
        int4 v = (gr >= batch0) ? *(const int4*)&zx[(size_t)gr * NPAD + 2 * D_INNER + seg * 8]
                                : (int4){0, 0, 0, 0};
        *(int4*)&sBCraw[r * 32 + seg * 8] = v;
    }
    if (t < 64) {
        float raw = b2f(zx[(size_t)(row0 + t) * NPAD + DT_COL + h]) + dt_bias[h];
        float dtv = (raw > 20.f) ? raw : log1pf(__expf(raw));
        float v = dtv;
        #pragma unroll
        for (int o = 1; o < 64; o <<= 1) {
            float u = __shfl_up(v, o, 64);
            if (t >= o) v += u;
        }
        sdt[t] = dtv;
        scd[t] = v;
        float sc = __expf(Ah * v);
        float* scrow = &scA[(size_t)(bh * NCHUNK + c) * 192];
        scrow[t] = dtv; scrow[64 + t] = v; scrow[128 + t] = sc;
        if (t == 63) pbuf[bh * NCHUNK + c] = sc;
    }
    __syncthreads();

    // ---- phase 2: conv + silu (sliding window) ----
    {   // X: thread owns column p, 16 s values
        const int p = t & 63, sblk = (t >> 6) * 16;
        const int ch = h * 64 + p;
        const float4 cw = *(const float4*)&conv_w[ch * 4];
        const float cb = conv_b[ch];
        float x0 = b2f(sXraw[(sblk + 0) * 64 + p]);
        float x1 = b2f(sXraw[(sblk + 1) * 64 + p]);
        float x2 = b2f(sXraw[(sblk + 2) * 64 + p]);
        #pragma unroll
        for (int i = 0; i < 16; i++) {
            float x3 = b2f(sXraw[(sblk + i + 3) * 64 + p]);
            float acc = cb + cw.x * x0 + cw.y * x1 + cw.z * x2 + cw.w * x3;
            float sv = acc / (1.f + __expf(-acc));
            sXT[p * 72 + sblk + i] = f2b(sv);
            x0 = x1; x1 = x2; x2 = x3;
        }
    }
    {   // B/C: thread owns channel ch32, 8 s values; ch32<16 also writes weighted Bw^T
        const int ch32 = t & 31, s0 = (t >> 5) * 8;
        const int ch = D_INNER + ch32;
        const float4 cw = *(const float4*)&conv_w[ch * 4];
        const float cb = conv_b[ch];
        const float cdl = scd[63];
        float x0 = b2f(sBCraw[(s0 + 0) * 32 + ch32]);
        float x1 = b2f(sBCraw[(s0 + 1) * 32 + ch32]);
        float x2 = b2f(sBCraw[(s0 + 2) * 32 + ch32]);
        #pragma unroll
        for (int i = 0; i < 8; i++) {
            int s = s0 + i;
            float x3 = b2f(sBCraw[(s + 3) * 32 + ch32]);
            float acc = cb + cw.x * x0 + cw.y * x1 + cw.z * x2 + cw.w * x3;
            float sv = acc / (1.f + __expf(-acc));
            sBC[s * 32 + ch32] = f2b(sv);
            if (ch32 < 16) {
                float wgt = sdt[s] * __expf(Ah * (cdl - scd[s]));
                sBwT[ch32 * 72 + s] = f2b(sv * wgt);
            }
            x0 = x1; x1 = x2; x2 = x3;
        }
    }
    __syncthreads();

    // ---- phase 3: h_local = Bw^T X ----
    f32x4 hacc = (f32x4){0.f, 0.f, 0.f, 0.f};
    #pragma unroll
    for (int ks = 0; ks < 2; ks++) {
        bf16x8 af = *(const bf16x8*)&sBwT[lm * 72 + ks * 32 + lq8];
        bf16x8 bf_ = *(const bf16x8*)&sXT[(w * 16 + lm) * 72 + ks * 32 + lq8];
        hacc = __builtin_amdgcn_mfma_f32_16x16x32_bf16(af, bf_, hacc, 0, 0, 0);
    }
    #pragma unroll
    for (int r = 0; r < 4; r++)
        hbuf[(size_t)(bh * NCHUNK + c) * 1024 + (lq4 + r) * 64 + (w * 16 + lm)] = hacc[r];

    // ---- phase 4: persist conv outputs ----
    #pragma unroll
    for (int it = 0; it < 2; it++) {
        int idx = t + it * 256;          // 512 int4: row p = idx>>3, seg = idx&7
        int p = idx >> 3, seg = idx & 7;
        *(int4*)&xTg[(size_t)(bh * 64 + p) * SEQLEN + c * 64 + seg * 8] =
            *(const int4*)&sXT[p * 72 + seg * 8];
    }
    if (h == 0) {                        // bcg: 64 rows x 32 ch = 256 int4
        int s = t >> 2, seg = t & 3;
        *(int4*)&bcg[(size_t)(b * SEQLEN + c * 64 + s) * 32 + seg * 8] =
            *(const int4*)&sBC[s * 32 + seg * 8];
    }
}

// ---------- 5b. inter-chunk state scan: register-prefetched ----------
__global__ __launch_bounds__(1024)
void ssd_state_scan(float* __restrict__ hbuf, const float* __restrict__ pbuf) {
    int bh = blockIdx.x;
    int t = threadIdx.x;
    __shared__ float sP[NCHUNK];
    if (t < NCHUNK) sP[t] = pbuf[bh * NCHUNK + t];
    __syncthreads();
    size_t base = (size_t)bh * NCHUNK * 1024 + t;
    float v[NCHUNK];
    #pragma unroll
    for (int c = 0; c < NCHUNK; c++) v[c] = hbuf[base + (size_t)c * 1024];
    float carry = 0.f;
    #pragma unroll
    for (int c = 0; c < NCHUNK; c++) {
        float tmp = v[c];
        v[c] = carry;
        carry = tmp + sP[c] * carry;
    }
    #pragma unroll
    for (int c = 0; c < NCHUNK; c++) hbuf[base + (size_t)c * 1024] = v[c];
}

// ---------- 5c. y kernel (pure MFMA + epilogue): yq = fp8(YSCALE*(M.X + scale*(C.h_in))*silu(z)) ----------
// D*x folded into M's diagonal.
__global__ __launch_bounds__(256)
void ssd_yfused(const unsigned short* __restrict__ zx,
                const unsigned short* __restrict__ xTg, const unsigned short* __restrict__ bcg,
                const float* __restrict__ scA,
                const float* __restrict__ A_log, const float* __restrict__ D_param,
                const float* __restrict__ hbuf,
                unsigned char* __restrict__ y, float* __restrict__ ssq) {
    __shared__ unsigned short sXT[64 * 72];
    __shared__ unsigned short sM[64 * 72];
    __shared__ unsigned short sB[64 * 32];
    __shared__ unsigned short sC[64 * 32];
    __shared__ unsigned short sZ[64 * 64];
    __shared__ unsigned short sHT[64 * 40];
    __shared__ float sdt[64], scd[64], sSc[64];

    const int blk = blockIdx.x;
    const int c  = blk & 31;
    const int h  = (blk >> 5) & 31;
    const int b  = blk >> 10;
    const int bh = blk >> 5;
    const int row0 = b * SEQLEN + c * QCHUNK;

    const int t    = threadIdx.x;
    const int w    = t >> 6;
    const int lane = t & 63;
    const int lm   = lane & 15;
    const int lq8  = (lane >> 4) * 8;
    const int lq4  = (lane >> 4) * 4;
    const float Ah = -__expf(A_log[h]);

    // ---- staging (all vector loads) ----
    #pragma unroll
    for (int it = 0; it < 2; it++) {
        int idx = t + it * 256;          // X^T: 512 int4
        int p = idx >> 3, seg = idx & 7;
        *(int4*)&sXT[p * 72 + seg * 8] =
            *(const int4*)&xTg[(size_t)(bh * 64 + p) * SEQLEN + c * 64 + seg * 8];
    }
    #pragma unroll
    for (int it = 0; it < 2; it++) {
        int idx = t + it * 256;          // z: 512 int4
        int s = idx >> 3, seg = idx & 7;
        *(int4*)&sZ[s * 64 + seg * 8] =
            *(const int4*)&zx[(size_t)(row0 + s) * NPAD + h * 64 + seg * 8];
    }
    {                                    // B/C: 256 int4
        int s = t >> 2, seg = t & 3;
        int4 v = *(const int4*)&bcg[(size_t)(b * SEQLEN + c * 64 + s) * 32 + seg * 8];
        if (seg < 2) *(int4*)&sB[s * 32 + seg * 8] = v;
        else         *(int4*)&sC[s * 32 + (seg - 2) * 8] = v;
    }
    {                                    // h_in -> sHT [p][n] bf16
        size_t hb = (size_t)(bh * NCHUNK + c) * 1024 + (size_t)t * 4;
        float4 hv = *(const float4*)&hbuf[hb];
        int n = t >> 4;
        int p0 = (t * 4) & 63;
        sHT[(p0 + 0) * 40 + n] = f2b(hv.x);
        sHT[(p0 + 1) * 40 + n] = f2b(hv.y);
        sHT[(p0 + 2) * 40 + n] = f2b(hv.z);
        sHT[(p0 + 3) * 40 + n] = f2b(hv.w);
    }
    if (t < 64) {                        // pads
        *(int4*)&sB[t * 32 + 16] = (int4){0, 0, 0, 0};
        *(int4*)&sB[t * 32 + 24] = (int4){0, 0, 0, 0};
        *(int4*)&sC[t * 32 + 16] = (int4){0, 0, 0, 0};
        *(int4*)&sC[t * 32 + 24] = (int4){0, 0, 0, 0};
        *(int4*)&sHT[t * 40 + 16] = (int4){0, 0, 0, 0};
        *(int4*)&sHT[t * 40 + 24] = (int4){0, 0, 0, 0};
    }
    if (t < 192) {                       // dt / cd / scale
        float v = scA[(size_t)(bh * NCHUNK + c) * 192 + t];
        if (t < 64) sdt[t] = v;
        else if (t < 128) scd[t - 64] = v;
        else sSc[t - 128] = v;
    }
    __syncthreads();

    // ---- S = C * B^T (lower-triangular blocks) ----
    f32x4 sacc[4];
    {
        bf16x8 cfrag = *(const bf16x8*)&sC[(w * 16 + lm) * 32 + lq8];
        #pragma unroll
        for (int sb = 0; sb < 4; sb++) {
            if (sb <= w) {
                bf16x8 bfrag = *(const bf16x8*)&sB[(sb * 16 + lm) * 32 + lq8];
                sacc[sb] = __builtin_amdgcn_mfma_f32_16x16x32_bf16(
                    cfrag, bfrag, (f32x4){0.f, 0.f, 0.f, 0.f}, 0, 0, 0);
            }
        }
    }
    // ---- M[t][s] with D on the diagonal ----
    const float Dh = D_param[h];
    #pragma unroll
    for (int sb = 0; sb < 4; sb++) {
        int sp = sb * 16 + lm;
        if (sb > w) {
            #pragma unroll
            for (int r = 0; r < 4; r++) sM[(w * 16 + lq4 + r) * 72 + sp] = 0;
        } else {
            float dts = sdt[sp], cds = scd[sp];
            #pragma unroll
            for (int r = 0; r < 4; r++) {
                int tp = w * 16 + lq4 + r;
                float m = 0.f;
                if (sb < w || sp <= tp) {
                    m = sacc[sb][r] * dts * __expf(Ah * (scd[tp] - cds));
                    if (sp == tp) m += Dh;
                }
                sM[tp * 72 + sp] = f2b(m);
            }
        }
    }

    // ---- Y1 = M * X ----
    f32x4 yacc[4];
    #pragma unroll
    for (int pb = 0; pb < 4; pb++) yacc[pb] = (f32x4){0.f, 0.f, 0.f, 0.f};
    #pragma unroll
    for (int ks = 0; ks < 2; ks++) {
        if (ks == 1 && w < 2) continue;
        bf16x8 af = *(const bf16x8*)&sM[(w * 16 + lm) * 72 + ks * 32 + lq8];
        #pragma unroll
        for (int pb = 0; pb < 4; pb++) {
            bf16x8 bf_ = *(const bf16x8*)&sXT[(pb * 16 + lm) * 72 + ks * 32 + lq8];
            yacc[pb] = __builtin_amdgcn_mfma_f32_16x16x32_bf16(af, bf_, yacc[pb], 0, 0, 0);
        }
    }
    // ---- Y2 = C * h_in^T ----
    f32x4 acc2[4];
    {
        bf16x8 cf2 = *(const bf16x8*)&sC[(w * 16 + lm) * 32 + lq8];
        #pragma unroll
        for (int pb = 0; pb < 4; pb++) {
            bf16x8 hf = *(const bf16x8*)&sHT[(pb * 16 + lm) * 40 + lq8];
            acc2[pb] = __builtin_amdgcn_mfma_f32_16x16x32_bf16(
                cf2, hf, (f32x4){0.f, 0.f, 0.f, 0.f}, 0, 0, 0);
        }
    }

    // ---- epilogue: z-gate, fp8 store, ssq partials ----
    #pragma unroll
    for (int r = 0; r < 4; r++) {
        const int tp = w * 16 + lq4 + r;
        const size_t yrow = (size_t)(row0 + tp) * D_INNER + h * 64;
        float ssr = 0.f;
        #pragma unroll
        for (int pb = 0; pb < 4; pb++) {
            int pp = pb * 16 + lm;
            float val = yacc[pb][r] + sSc[tp] * acc2[pb][r];
            float zv = b2f(sZ[tp * 64 + pp]);
            float yg = val * (zv / (1.f + __expf(-zv)));
            ssr += yg * yg;
            y[yrow + pp] = f2fp8(yg * YSCALE);
        }
        ssr += __shfl_xor(ssr, 1, 16);
        ssr += __shfl_xor(ssr, 2, 16);
        ssr += __shfl_xor(ssr, 4, 16);
        ssr += __shfl_xor(ssr, 8, 16);
        if (lm == 0)
            ssq[(size_t)(row0 + tp) * NHEADS + h] = ssr;
    }
}

// ---------- 5d. per-row rsqrt scale ----------
__global__ __launch_bounds__(256)
void rowscale_kernel(const float* __restrict__ ssq, float* __restrict__ rs) {
    int row = blockIdx.x * 256 + threadIdx.x;
    const float4* p = (const float4*)&ssq[(size_t)row * NHEADS];
    float s = 0.f;
    #pragma unroll
    for (int i = 0; i < 8; i++) {
        float4 v = p[i];
        s += v.x + v.y + v.z + v.w;
    }
    rs[row] = rsqrtf(s * (1.f / D_INNER) + 1e-5f);
}

// ---------- launcher ----------
extern "C" void kernel_launch(void* const* d_in, const int* in_sizes, int n_in,
                              void* d_out, int out_size, void* d_ws, size_t ws_size,
                              hipStream_t stream) {
    const float* x        = (const float*)d_in[0];
    const float* W_in     = (const float*)d_in[1];
    const float* conv_w   = (const float*)d_in[2];
    const float* conv_b   = (const float*)d_in[3];
    const float* dt_bias  = (const float*)d_in[4];
    const float* A_log    = (const float*)d_in[5];
    const float* D_param  = (const float*)d_in[6];
    const float* norm_w   = (const float*)d_in[7];
    const float* W_out    = (const float*)d_in[8];
    const float* ls       = (const float*)d_in[9];
    float* out = (float*)d_out;

    char* ws = (char*)d_ws;
    size_t off = 0;
    unsigned char*  x_f8  = (unsigned char*)(ws + off);  off += (size_t)MROWS * D_MODEL;       // 8.4 MB
    unsigned char*  winT  = (unsigned char*)(ws + off);  off += (size_t)NPAD * D_MODEL;        // 4.3 MB
    unsigned char*  woutT = (unsigned char*)(ws + off);  off += (size_t)D_MODEL * D_INNER;     // 2.1 MB
    unsigned short* zx    = (unsigned short*)(ws + off); off += (size_t)MROWS * NPAD * 2;      // 69.2 MB
    float*          pbuf  = (float*)(ws + off);          off += (size_t)BATCH * NHEADS * NCHUNK * 4;
    unsigned char*  yb    = (unsigned char*)(ws + off);  off += (size_t)MROWS * D_INNER;       // 16.8 MB
    float*          ssq   = (float*)(ws + off);          off += (size_t)MROWS * NHEADS * 4;    // 1 MB
    float*          rsb   = (float*)(ws + off);          off += (size_t)MROWS * 4;
    float*          hbuf  = (float*)(ws + off);          off += (size_t)BATCH * NHEADS * NCHUNK * 1024 * 4; // 16.8 MB
    unsigned short* xTg   = (unsigned short*)(ws + off); off += (size_t)MROWS * D_INNER * 2;   // 33.5 MB
    unsigned short* bcg   = (unsigned short*)(ws + off); off += (size_t)MROWS * 32 * 2;        // 0.5 MB
    float*          scA   = (float*)(ws + off);          off += (size_t)BATCH * NHEADS * NCHUNK * 192 * 4; // 3.1 MB

    cast_f32_fp8<<<(MROWS * D_MODEL) / 1024, 256, 0, stream>>>(x, x_f8, MROWS * D_MODEL);
    transpose_both<<<1568, 256, 0, stream>>>(W_in, winT, W_out, woutT, norm_w);
    gemm_fp8<0><<<(NPAD / 128) * 64, 256, 0, stream>>>(
        x_f8, winT, D_MODEL, NPAD, zx, nullptr, nullptr, nullptr, nullptr);
    ssd_hcomp<<<BATCH * NHEADS * NCHUNK, 256, 0, stream>>>(
        zx, dt_bias, conv_w, conv_b, A_log, hbuf, pbuf, xTg, bcg, scA);
    ssd_state_scan<<<BATCH * NHEADS, 1024, 0, stream>>>(hbuf, pbuf);
    ssd_yfused<<<BATCH * NHEADS * NCHUNK, 256, 0, stream>>>(
        zx, xTg, bcg, scA, A_log, D_param, hbuf, yb, ssq);
    rowscale_kernel<<<MROWS / 256, 256, 0, stream>>>(ssq, rsb);
    gemm_fp8<1><<<(D_MODEL / 128) * 64, 256, 0, stream>>>(
        yb, woutT, D_INNER, D_MODEL, nullptr, out, x, ls, rsb);
}